// Round 9
// baseline (1432.069 us; speedup 1.0000x reference)
//
#include <hip/hip_runtime.h>
#include <stdint.h>

typedef unsigned short u16;
typedef __bf16 bf16x8 __attribute__((ext_vector_type(8)));
typedef float f32x4 __attribute__((ext_vector_type(4)));

// f32 inputs/outputs (verified R2). GEMMs run bf16 MFMA (absmax 0.0156 << 0.05).
// R4: compile-time acc idx / swizzled LDS / occupancy cliffs at 64/128/256 VGPR.
// R5: counted-vmcnt graft on 2-barrier loop = null (regime gate).
// R6: m201-style BK=64 dbuf + counted vmcnt: gemm_gru 209.6->185.8us.
// R7: 2 independent 256-thr blocks/CU: gemm_gru 170.6us. prep split done (R9-12).
// R8 data: gemm_gru MfmaUtil 40%, Occ 20.5% (8 waves/CU), both pipes <25% utilized,
//     ~2130cy per block-K-tile vs ~600cy issue footprint => LATENCY-CHAIN bound.
// R13: BK=32 + packed LDS rows (A-rows {r,r+64} share a 128B LDS row; B {j,j+32})
//     keeps the proven conflict-free swizzle, LDS 80->40KB => 4 blocks/CU (16 waves).
//     Uniform 5 gloads/thread/tile, vmcnt(5) steady state. Wave tile unchanged.

__device__ __forceinline__ float bf2f(unsigned u) { return __uint_as_float(u << 16); }
__device__ __forceinline__ u16 f2bf(float f) {
  unsigned x = __float_as_uint(f);
  unsigned r = x + 0x7fffu + ((x >> 16) & 1u);
  return (u16)(r >> 16);
}
__device__ __forceinline__ unsigned pack2(float a, float b) {
  return (unsigned)f2bf(a) | ((unsigned)f2bf(b) << 16);
}
__device__ __forceinline__ float sigm(float x) { return 1.f / (1.f + __expf(-x)); }
__device__ __forceinline__ float fast_tanh(float x) {
  float e = __expf(2.f * x);
  return 1.f - 2.f / (e + 1.f);
}

#define AS1(p) ((const __attribute__((address_space(1))) void*)(p))
#define AS3(p) ((__attribute__((address_space(3))) void*)(p))

#define NC 16384

// =====================================================================
// prep_cvt: hid f32 -> bf16, 2048 blocks x 256 thr, 8 chunks/thread.
// =====================================================================
__global__ __launch_bounds__(256) void prep_cvt(const float* __restrict__ hid,
                                                u16* __restrict__ hidc) {
  int b = blockIdx.x, t = threadIdx.x;
  const float4* src = (const float4*)hid;
  uint2* dst = (uint2*)hidc;
#pragma unroll
  for (int c = 0; c < 8; ++c) {
    float4 v = src[(size_t)(b + c * 2048) * 256 + t];
    uint2 o; o.x = pack2(v.x, v.y); o.y = pack2(v.z, v.w);
    dst[(size_t)(b + c * 2048) * 256 + t] = o;
  }
}

// =====================================================================
// prep_packT: weight transposes, 1248 blocks.
// =====================================================================
__device__ __forceinline__ void packT_body(
    const float* __restrict__ src, int sld, int srow0,
    u16* __restrict__ dst, int dld, int drow0, int koff,
    int remapThresh, int remapAdd, float sgn, int bx, int by,
    float (*tile)[65], int t) {
  const int k0 = by * 64, c0 = bx * 64;
  const int tx = t & 15, ty = t >> 4;
#pragma unroll
  for (int p = 0; p < 4; ++p) {
    int r = ty + p * 16;
    float4 v = *reinterpret_cast<const float4*>(&src[(size_t)(srow0 + k0 + r) * sld + c0 + tx * 4]);
    tile[tx * 4 + 0][r] = v.x;
    tile[tx * 4 + 1][r] = v.y;
    tile[tx * 4 + 2][r] = v.z;
    tile[tx * 4 + 3][r] = v.w;
  }
  __syncthreads();
  const int cl = t >> 2;
  const int kb = (t & 3) * 16;
  int col = c0 + cl;
  int row = drow0 + col + ((col >= remapThresh) ? remapAdd : 0);
  union { u16 o[16]; uint4 v[2]; } u;
#pragma unroll
  for (int e = 0; e < 16; ++e) u.o[e] = f2bf(sgn * tile[cl][kb + e]);
  uint4* d = reinterpret_cast<uint4*>(&dst[(size_t)row * dld + koff + k0 + kb]);
  d[0] = u.v[0]; d[1] = u.v[1];
}

__global__ __launch_bounds__(256) void prep_packT(
    const float* __restrict__ W_ih, const float* __restrict__ W_hh, u16* __restrict__ WgruT,
    const float* __restrict__ Wa1, const float* __restrict__ Wg1, u16* __restrict__ W1catT,
    const float* __restrict__ Wa2, const float* __restrict__ Wg2, u16* __restrict__ W2catT) {
  __shared__ float tile[64][65];
  int b = blockIdx.x, t = threadIdx.x;
  if (b < 768) {  // W_hh (1024x3072) -> WgruT cols 512..; col>=2048 remaps +1024
    packT_body(W_hh, 3072, 0, WgruT, 1536, 0, 512, 2048, 1024, 1.f, b % 48, b / 48, tile, t);
    return;
  }
  b -= 768;
  if (b < 384) {  // W_ih rows 0..511 -> WgruT cols 0..511
    packT_body(W_ih, 3072, 0, WgruT, 1536, 0, 0, 1 << 30, 0, 1.f, b % 48, b / 48, tile, t);
    return;
  }
  b -= 384;
  if (b < 32) { packT_body(Wa1, 128, 512, W1catT, 1024, 0, 0, 1 << 30, 0, 1.f, b % 2, b / 2, tile, t); return; }
  b -= 32;
  if (b < 32) { packT_body(Wg1, 128, 512, W1catT, 1024, 128, 0, 1 << 30, 0, 1.f, b % 2, b / 2, tile, t); return; }
  b -= 32;
  if (b < 16) { packT_body(Wa2, 512, 0, W2catT, 256, 0, 0, 1 << 30, 0, 1.f, b % 8, b / 8, tile, t); return; }
  b -= 16;
  { packT_body(Wg2, 512, 0, W2catT, 256, 0, 128, 1 << 30, 0, -1.f, b % 8, b / 8, tile, t); }
}

// =====================================================================
// prep_small: bias1 (64 blocks, 8 unrolled k each) | bias2 (2) | counts (64).
// =====================================================================
__global__ __launch_bounds__(256) void prep_small(
    const float* __restrict__ Wa1, const float* __restrict__ Wg1,
    const float* __restrict__ x, const float* __restrict__ ba1, const float* __restrict__ bg1,
    float* __restrict__ bias1, const float* __restrict__ ba2, const float* __restrict__ bg2,
    float* __restrict__ bias2, const int* __restrict__ positions, int* __restrict__ counts) {
  int b = blockIdx.x, t = threadIdx.x;
  if (b < 64) {  // bias1: k-split 8 per block, unrolled independent loads
    const float* W = (t < 128) ? Wa1 : Wg1;
    int cc = t & 127;
    int k0 = b * 8;
    float wv[8], xv[8];
#pragma unroll
    for (int j = 0; j < 8; ++j) {
      xv[j] = x[k0 + j];
      wv[j] = W[(size_t)(k0 + j) * 128 + cc];
    }
    float acc = 0.f;
#pragma unroll
    for (int j = 0; j < 8; ++j) acc += xv[j] * wv[j];
    if (b == 0) acc += (t < 128) ? ba1[cc] : bg1[cc];
    atomicAdd(&bias1[t], acc);
    return;
  }
  b -= 64;
  if (b < 2) { int n = b * 256 + t; bias2[n] = ba2[n] - bg2[n]; return; }
  b -= 2;
  {
    int i = b * 256 + t;
    int p = positions[i], f = i >> 11;
    if (p > 0) atomicAdd(&counts[f * 2], 1);
    else if (p < 0) atomicAdd(&counts[f * 2 + 1], 1);
  }
}

// =====================================================================
// bf16 MFMA GEMM, 128x128, BK=32, XOR-swizzled LDS (slot = q ^ ((row>>1)&3)).
// Triple-buffered, depth-2 prefetch, counted vmcnt. epi 1: +bias,relu ;
// epi 3: +bias + fused per-row sum-of-squares -> tension.
// =====================================================================
__global__ __launch_bounds__(256) void gemm_bt(
    const u16* __restrict__ A, int lda,
    const u16* __restrict__ Bt, int ldb,
    u16* __restrict__ C, int ldc,
    const float* __restrict__ bias, int epi, int K,
    float* __restrict__ tension) {
  __shared__ __align__(16) u16 As[3][128 * 32];
  __shared__ __align__(16) u16 Bs[3][128 * 32];
  const int tid = threadIdx.x;
  const int m0 = blockIdx.x * 128;
  const int n0 = blockIdx.y * 128;
  f32x4 acc[4][4] = {};
  const int lane = tid & 63;
  const int w = tid >> 6;
  const int mw = (w & 1) * 64, nw = (w >> 1) * 64;
  const int fr = lane & 15;
  const int q = lane >> 4;
  const int ar0 = tid >> 2;                     // rows 0..63 (chunk tid), +64 for chunk tid+256
  const int ag = ((tid & 3) ^ ((ar0 >> 1) & 3)) * 8;  // (row+64)>>1 keeps same &3 -> ag reused

  const u16* aB0 = A + (size_t)(m0 + ar0) * lda + ag;
  const u16* aB1 = A + (size_t)(m0 + ar0 + 64) * lda + ag;
  const u16* bB0 = Bt + (size_t)(n0 + ar0) * ldb + ag;
  const u16* bB1 = Bt + (size_t)(n0 + ar0 + 64) * ldb + ag;

  auto stage = [&](int kk, int buf) {
    __builtin_amdgcn_global_load_lds(AS1(aB0 + kk), AS3(&As[buf][tid * 8]), 16, 0, 0);
    __builtin_amdgcn_global_load_lds(AS1(aB1 + kk), AS3(&As[buf][(tid + 256) * 8]), 16, 0, 0);
    __builtin_amdgcn_global_load_lds(AS1(bB0 + kk), AS3(&Bs[buf][tid * 8]), 16, 0, 0);
    __builtin_amdgcn_global_load_lds(AS1(bB1 + kk), AS3(&Bs[buf][(tid + 256) * 8]), 16, 0, 0);
  };

  const int NT = K >> 5;   // >= 8 for all calls
  stage(0, 0);
  stage(32, 1);
  int cur = 0, nxt = 1, nx2 = 2;
#pragma unroll 1
  for (int t = 0; t < NT; ++t) {
    if (t + 2 < NT) stage((t + 2) * 32, nx2);
    const int rem = NT - 1 - t;  // tiles newer than t in flight
    if (rem >= 2)      asm volatile("s_waitcnt vmcnt(8)" ::: "memory");
    else if (rem == 1) asm volatile("s_waitcnt vmcnt(4)" ::: "memory");
    else               asm volatile("s_waitcnt vmcnt(0)" ::: "memory");
    __builtin_amdgcn_s_barrier();          // tile t fully in LDS (all waves)
    asm volatile("" ::: "memory");
    bf16x8 af[4], bfv[4];
#pragma unroll
    for (int mt = 0; mt < 4; ++mt) {
      int r = mw + mt * 16 + fr;
      af[mt] = *reinterpret_cast<const bf16x8*>(&As[cur][r * 32 + ((q ^ ((r >> 1) & 3)) * 8)]);
    }
#pragma unroll
    for (int nt = 0; nt < 4; ++nt) {
      int r = nw + nt * 16 + fr;
      bfv[nt] = *reinterpret_cast<const bf16x8*>(&Bs[cur][r * 32 + ((q ^ ((r >> 1) & 3)) * 8)]);
    }
    __builtin_amdgcn_s_setprio(1);
#pragma unroll
    for (int mt = 0; mt < 4; ++mt)
#pragma unroll
      for (int nt = 0; nt < 4; ++nt)
        acc[mt][nt] = __builtin_amdgcn_mfma_f32_16x16x32_bf16(af[mt], bfv[nt], acc[mt][nt], 0, 0, 0);
    __builtin_amdgcn_s_setprio(0);
    asm volatile("s_waitcnt lgkmcnt(0)" ::: "memory");  // my ds_reads retired
    __builtin_amdgcn_s_barrier();          // buf[cur] safe to overwrite at t+1
    int tmp = cur; cur = nxt; nxt = nx2; nx2 = tmp;
  }
  const int rq = q * 4;  // D: col=lane&15, row=rq+reg [m89]
#pragma unroll
  for (int mt = 0; mt < 4; ++mt) {
    float srow[4] = {0.f, 0.f, 0.f, 0.f};
#pragma unroll
    for (int nt = 0; nt < 4; ++nt) {
      int col = n0 + nw + nt * 16 + fr;
      f32x4 v = acc[mt][nt];
#pragma unroll
      for (int r = 0; r < 4; ++r) {
        int row = m0 + mw + mt * 16 + rq + r;
        float val = v[r] + bias[col];
        if (epi == 1) val = val > 0.f ? val : 0.f;
        else srow[r] += val * val;
        C[(size_t)row * ldc + col] = f2bf(val);
      }
    }
    if (epi == 3) {
#pragma unroll
      for (int r = 0; r < 4; ++r) {
        float s = srow[r];
        s += __shfl_xor(s, 1, 16); s += __shfl_xor(s, 2, 16);
        s += __shfl_xor(s, 4, 16); s += __shfl_xor(s, 8, 16);
        if (fr == 0) atomicAdd(&tension[m0 + mw + mt * 16 + rq + r], s);
      }
    }
  }
}

// =====================================================================
// R13 fused GRU. 256 threads / 4 waves; block tile 128 rows x 64 j x 4 reg;
// BK=32; wave = 64 rows x 32 j x 4 reg (acc[4][4][2] = 128 VGPR).
// LDS 40KB => 4 blocks/CU (16 waves): As[2][64][64] u16 (row r' packs A-rows
// {r', r'+64}), Bs[2][3][32][64] (row r' packs B-rows {r', r'+32}).
// 8 swizzled 16B slots/row, s_phys = sidx ^ (r'&7); 128B row stride keeps the
// proven 2-way-free bank profile. Staging: 5 gloads/thread/tile (2 A + 3 B),
// depth-2 prefetch, vmcnt(5) steady state (each wave drains its own loads
// before the barrier => all staged data visible after barrier).
// Per K-tile: 10 ds_read -> lgkm0 -> bar -> STAGE(t+2) -> 24 MFMA -> vmcnt(5) -> bar.
// Tiles 0..15: A=outbf, reg3=gi_n(rows 2048+); 16..47: A=hidc, reg3=gh_n(3072+).
// WgruT K-offset = T*32 uniform; A K-offset = (T<16 ? T : T-16)*32.
// =====================================================================
__global__ __launch_bounds__(256, 4) void gemm_gru(
    const u16* __restrict__ outbf, const u16* __restrict__ hidc,
    const u16* __restrict__ WgruT,
    const float* __restrict__ W_ihf, const float* __restrict__ bihf,
    const float* __restrict__ bhhf, const float* __restrict__ wealthf,
    const float* __restrict__ tension, u16* __restrict__ hpre) {
  __shared__ __align__(16) u16 As[2][64 * 64];
  __shared__ __align__(16) u16 Bs[2][3][32 * 64];
  const int tid = threadIdx.x;
  const int m0 = blockIdx.x * 128;
  const int j0 = blockIdx.y * 64;
  f32x4 acc[4][4][2] = {};  // [region][mt][nt]
  const int lane = tid & 63;
  const int w = tid >> 6;
  const int mw = (w & 1) * 64, jw = (w >> 1) * 32;
  const int fr = lane & 15;
  const int q = lane >> 4;
  const int f7 = fr & 7;
  // fragment slot offsets (u16): s_phys = (q + half*4) ^ f7 ; half is wave-fixed
  const int skA = ((q + (w & 1) * 4) ^ f7) * 8;
  const int skB = ((q + (w >> 1) * 4) ^ f7) * 8;
  // staging: chunk tid -> LDS 16B chunk tid; stored sidx = (tid&7) ^ ((tid>>3)&7)
  const int rl = tid >> 3;                    // LDS row 0..31
  const int sidx = (tid & 7) ^ (rl & 7);
  const int kcol = (sidx & 3) * 8;
  const int ah = (sidx >= 4) ? 64 : 0;        // A packs rows {r', r'+64}
  const int bh = (sidx >= 4) ? 32 : 0;        // B packs rows {j', j'+32}
  const size_t aOut1 = (size_t)(m0 + rl + ah) * 512 + kcol;   // load1: LDS rows 0..31
  const size_t aOut2 = aOut1 + (size_t)32 * 512;              // load2: LDS rows 32..63
  const size_t aHid1 = (size_t)(m0 + rl + ah) * 1024 + kcol;
  const size_t aHid2 = aHid1 + (size_t)32 * 1024;
  const size_t bBase = (size_t)(j0 + rl + bh) * 1536 + kcol;

// sA keeps the untaken branch's constant-folded A offset non-negative (R11).
#define STAGE(S, BUF)                                                                              \
  {                                                                                                \
    const int sA = (S) < 16 ? (S) : (S) - 16;                                                      \
    const size_t kOA = (size_t)sA * 32;                                                            \
    const size_t kOB = (size_t)(S) * 32;                                                           \
    if ((S) < 16) {                                                                                \
      __builtin_amdgcn_global_load_lds(AS1(outbf + aOut1 + kOA), AS3(&As[BUF][tid * 8]), 16, 0, 0);\
      __builtin_amdgcn_global_load_lds(AS1(outbf + aOut2 + kOA),                                   \
                                       AS3(&As[BUF][2048 + tid * 8]), 16, 0, 0);                   \
    } else {                                                                                       \
      __builtin_amdgcn_global_load_lds(AS1(hidc + aHid1 + kOA), AS3(&As[BUF][tid * 8]), 16, 0, 0); \
      __builtin_amdgcn_global_load_lds(AS1(hidc + aHid2 + kOA),                                    \
                                       AS3(&As[BUF][2048 + tid * 8]), 16, 0, 0);                   \
    }                                                                                              \
    const u16* bp = WgruT + bBase + kOB;                                                           \
    __builtin_amdgcn_global_load_lds(AS1(bp), AS3(&Bs[BUF][0][tid * 8]), 16, 0, 0);                \
    __builtin_amdgcn_global_load_lds(AS1(bp + (size_t)1024 * 1536),                                \
                                     AS3(&Bs[BUF][1][tid * 8]), 16, 0, 0);                         \
    __builtin_amdgcn_global_load_lds(AS1(bp + (size_t)((S) < 16 ? 2048 : 3072) * 1536),            \
                                     AS3(&Bs[BUF][2][tid * 8]), 16, 0, 0);                         \
  }

#define GRU_STEP(T, REG3, CUR)                                                                     \
  {                                                                                                \
    bf16x8 af[4], b0v[2], b1v[2], b2v[2];                                                          \
    _Pragma("unroll") for (int mt = 0; mt < 4; ++mt)                                               \
        af[mt] = *reinterpret_cast<const bf16x8*>(&As[CUR][(mt * 16 + fr) * 64 + skA]);            \
    _Pragma("unroll") for (int nt = 0; nt < 2; ++nt) {                                             \
      int rj = (nt * 16 + fr) * 64 + skB;                                                          \
      b0v[nt] = *reinterpret_cast<const bf16x8*>(&Bs[CUR][0][rj]);                                 \
      b1v[nt] = *reinterpret_cast<const bf16x8*>(&Bs[CUR][1][rj]);                                 \
      b2v[nt] = *reinterpret_cast<const bf16x8*>(&Bs[CUR][2][rj]);                                 \
    }                                                                                              \
    asm volatile("s_waitcnt lgkmcnt(0)" ::: "memory");                                             \
    __builtin_amdgcn_s_barrier();                                                                  \
    asm volatile("" ::: "memory");                                                                 \
    if ((T) + 2 < 48) { STAGE((T) + 2, CUR) }                                                      \
    __builtin_amdgcn_s_setprio(1);                                                                 \
    _Pragma("unroll") for (int mt = 0; mt < 4; ++mt)                                               \
        _Pragma("unroll") for (int nt = 0; nt < 2; ++nt) {                                         \
      acc[0][mt][nt] = __builtin_amdgcn_mfma_f32_16x16x32_bf16(af[mt], b0v[nt], acc[0][mt][nt], 0, 0, 0); \
      acc[1][mt][nt] = __builtin_amdgcn_mfma_f32_16x16x32_bf16(af[mt], b1v[nt], acc[1][mt][nt], 0, 0, 0); \
      acc[REG3][mt][nt] = __builtin_amdgcn_mfma_f32_16x16x32_bf16(af[mt], b2v[nt], acc[REG3][mt][nt], 0, 0, 0); \
    }                                                                                              \
    __builtin_amdgcn_s_setprio(0);                                                                 \
    if ((T) + 2 < 48)      { asm volatile("s_waitcnt vmcnt(5)" ::: "memory"); }                    \
    else if ((T) + 1 < 48) { asm volatile("s_waitcnt vmcnt(0)" ::: "memory"); }                    \
    __builtin_amdgcn_s_barrier();                                                                  \
    asm volatile("" ::: "memory");                                                                 \
  }

  STAGE(0, 0)
  STAGE(1, 1)
  asm volatile("s_waitcnt vmcnt(5)" ::: "memory");
  __builtin_amdgcn_s_barrier();
  asm volatile("" ::: "memory");
#pragma unroll 1
  for (int T = 0; T < 16; T += 2) {   // tiles 0..15: reg3 = gi_n
    GRU_STEP(T, 2, 0)
    GRU_STEP(T + 1, 2, 1)
  }
#pragma unroll 1
  for (int T = 16; T < 48; T += 2) {  // tiles 16..47: reg3 = gh_n
    GRU_STEP(T, 3, 0)
    GRU_STEP(T + 1, 3, 1)
  }
#undef GRU_STEP
#undef STAGE

  // epilogue: D col=lane&15, row=(lane>>4)*4+reg [m89]
  const int rq = q * 4;
  const float* wt = W_ihf + (size_t)512 * 3072;  // tension row
  float wtr[2], wtz[2], wtn[2], bir[2], biz[2], bin_[2], bhr_[2], bhz_[2], bhn_[2];
#pragma unroll
  for (int nt = 0; nt < 2; ++nt) {
    int j = j0 + jw + nt * 16 + fr;
    wtr[nt] = wt[j]; wtz[nt] = wt[1024 + j]; wtn[nt] = wt[2048 + j];
    bir[nt] = bihf[j]; biz[nt] = bihf[1024 + j]; bin_[nt] = bihf[2048 + j];
    bhr_[nt] = bhhf[j]; bhz_[nt] = bhhf[1024 + j]; bhn_[nt] = bhhf[2048 + j];
  }
#pragma unroll
  for (int mt = 0; mt < 4; ++mt) {
#pragma unroll
    for (int rr = 0; rr < 4; ++rr) {
      int row = m0 + mw + mt * 16 + rq + rr;
      float tv = tension[row] * (1.f / 512.f);
      float wl = fminf(fmaxf(wealthf[row], 0.1f), 2.0f);
      float mod = 0.9f + 0.1f * wl;
#pragma unroll
      for (int nt = 0; nt < 2; ++nt) {
        int j = j0 + jw + nt * 16 + fr;
        float r = sigm(acc[0][mt][nt][rr] + tv * wtr[nt] + bir[nt] + bhr_[nt]);
        float z = sigm(acc[1][mt][nt][rr] + tv * wtz[nt] + biz[nt] + bhz_[nt]);
        float n = fast_tanh(acc[2][mt][nt][rr] + tv * wtn[nt] + bin_[nt]
                            + r * (acc[3][mt][nt][rr] + bhn_[nt]));
        float h = bf2f(hidc[(size_t)row * 1024 + j]);
        float h2 = (1.f - z) * n + z * h;
        h2 = fminf(fmaxf(h2 * mod, -10.f), 10.f);
        hpre[(size_t)row * 1024 + j] = f2bf(h2);
      }
    }
  }
}

// =====================================================================
__global__ void stats_kernel(const u16* __restrict__ hpre, const int* __restrict__ positions,
                             float* __restrict__ fsums) {
  int cc = blockIdx.x, f = blockIdx.y, z = blockIdx.z, t = threadIdx.x;
  int col = cc * 128 + (t & 127);
  int half = t >> 7;
  float st = 0, sp = 0, sm = 0;
  for (int it = 0; it < 128; ++it) {
    int row = (f << 11) + ((z * 128 + it) << 1) + half;
    int p = positions[row];
    float v = bf2f(hpre[(size_t)row * 1024 + col]);
    st += v;
    if (p > 0) sp += v;
    if (p < 0) sm += v;
  }
  atomicAdd(&fsums[(f * 3 + 0) * 1024 + col], st);
  atomicAdd(&fsums[(f * 3 + 1) * 1024 + col], sp);
  atomicAdd(&fsums[(f * 3 + 2) * 1024 + col], sm);
}

__global__ void derive_kernel(const float* __restrict__ fsums, const int* __restrict__ counts,
                              float* __restrict__ mean1, float* __restrict__ mean2,
                              float* __restrict__ fmean, float* __restrict__ gop,
                              float* __restrict__ scal) {
  int c = threadIdx.x;  // 1024
  int cnt1 = 0, cnt2 = 0, cf1[8], cf2[8];
#pragma unroll
  for (int f = 0; f < 8; ++f) {
    cf1[f] = counts[f * 2]; cf2[f] = counts[f * 2 + 1];
    cnt1 += cf1[f]; cnt2 += cf2[f];
  }
  float s1 = 0, s2 = 0;
#pragma unroll
  for (int f = 0; f < 8; ++f) { s1 += fsums[(f * 3 + 1) * 1024 + c]; s2 += fsums[(f * 3 + 2) * 1024 + c]; }
  float m1 = s1 / (float)(cnt1 > 1 ? cnt1 : 1);
  float m2 = s2 / (float)(cnt2 > 1 ? cnt2 : 1);
  float a1 = (cnt1 >= 2) ? 0.1f : 0.f;
  float a2 = (cnt2 >= 2) ? 0.1f : 0.f;
  float g = 0;
#pragma unroll
  for (int f = 0; f < 8; ++f) {
    float fm = (fsums[(f * 3) * 1024 + c]
                + a1 * ((float)cf1[f] * m1 - fsums[(f * 3 + 1) * 1024 + c])
                + a2 * ((float)cf2[f] * m2 - fsums[(f * 3 + 2) * 1024 + c])) * (1.f / 2048.f);
    fmean[f * 1024 + c] = fm;
    g += fm;
  }
  gop[c] = g * 0.125f;
  mean1[c] = m1; mean2[c] = m2;
  if (c == 0) { scal[0] = a1; scal[1] = a2; }
}

// 2048 blocks x 256 thr; block handles 8 rows x 1024 cols (4 col-slices).
__global__ void finalize_kernel(const u16* __restrict__ hpre, const int* __restrict__ positions,
                                const int* __restrict__ step, const float* __restrict__ mean1,
                                const float* __restrict__ mean2, const float* __restrict__ fmean,
                                const float* __restrict__ gop, const float* __restrict__ scal,
                                float* __restrict__ out) {
  int t = threadIdx.x;
  int r0 = blockIdx.x * 8;
  float s0 = scal[0], s1 = scal[1];
  bool step5 = step[0] > 5;
#pragma unroll 2
  for (int rr = 0; rr < 8; ++rr) {
    int row = r0 + rr;
    int p = positions[row];
    float w1 = (p > 0) ? s0 : 0.f;
    float w2 = (p < 0) ? s1 : 0.f;
    int f = row >> 11, qq = row & 2047;
    bool deb = step5 && (qq < 512);
    const u16* hrow = hpre + (size_t)row * 1024;
    const float* fmp = fmean + f * 1024;
    float* orow = out + 513 + (size_t)row * 1024;
#pragma unroll
    for (int e = 0; e < 4; ++e) {
      int c = e * 256 + t;
      float h = bf2f(hrow[c]);
      float hgs = h + w1 * (mean1[c] - h) + w2 * (mean2[c] - h);
      float hfs = 0.85f * hgs + 0.15f * fmp[c];
      orow[c] = deb ? (0.85f * hfs + 0.15f * gop[c]) : hfs;
    }
  }
}

__global__ void softmax_kernel(const float* __restrict__ tension, float* __restrict__ weights,
                               float* __restrict__ out) {
  __shared__ float red[1024];
  int t = threadIdx.x;
  float tv[16], mx = -1e30f, sumt = 0.f;
#pragma unroll
  for (int k = 0; k < 16; ++k) {
    tv[k] = tension[t + k * 1024] * (1.f / 512.f);
    mx = fmaxf(mx, tv[k]); sumt += tv[k];
  }
  red[t] = mx; __syncthreads();
  for (int s = 512; s > 0; s >>= 1) { if (t < s) red[t] = fmaxf(red[t], red[t + s]); __syncthreads(); }
  float m = red[0]; __syncthreads();
  red[t] = sumt; __syncthreads();
  for (int s = 512; s > 0; s >>= 1) { if (t < s) red[t] += red[t + s]; __syncthreads(); }
  float tot = red[0]; __syncthreads();
  float ev[16], se = 0.f;
#pragma unroll
  for (int k = 0; k < 16; ++k) { ev[k] = __expf(tv[k] - m); se += ev[k]; }
  red[t] = se; __syncthreads();
  for (int s = 512; s > 0; s >>= 1) { if (t < s) red[t] += red[t + s]; __syncthreads(); }
  float invS = 1.f / red[0];
#pragma unroll
  for (int k = 0; k < 16; ++k) weights[t + k * 1024] = ev[k] * invS;
  if (t == 0) out[512] = tot * (1.f / 16384.f);
}

__global__ void wsum_kernel(const float* __restrict__ weights, const u16* __restrict__ outbf,
                            float* __restrict__ co) {
  int b = blockIdx.x, t = threadIdx.x;
  int c = t * 2;
  float a0 = 0.f, a1 = 0.f;
  int i0 = b * 128;
  for (int i = i0; i < i0 + 128; ++i) {
    float w = weights[i];
    unsigned v = *reinterpret_cast<const unsigned*>(outbf + (size_t)i * 512 + c);
    a0 += w * bf2f(v & 0xffff);
    a1 += w * bf2f(v >> 16);
  }
  atomicAdd(&co[c], a0);
  atomicAdd(&co[c + 1], a1);
}

__global__ void pred_kernel(const float* __restrict__ co, const float* __restrict__ Wof,
                            const float* __restrict__ bof, float* __restrict__ out) {
  __shared__ float cs[512];
  int t = threadIdx.x, n = blockIdx.x * 256 + t;
  cs[t] = co[t]; cs[t + 256] = co[t + 256];
  __syncthreads();
  float acc = bof[n];
  for (int ck = 0; ck < 512; ++ck) acc += cs[ck] * Wof[(size_t)ck * 512 + n];
  out[n] = acc;
}

// =====================================================================
extern "C" void kernel_launch(void* const* d_in, const int* in_sizes, int n_in,
                              void* d_out, int out_size, void* d_ws, size_t ws_size,
                              hipStream_t stream) {
  const float* x      = (const float*)d_in[0];
  const float* hid    = (const float*)d_in[1];
  const float* wealth = (const float*)d_in[2];
  const float* Wa1    = (const float*)d_in[3];
  const float* ba1    = (const float*)d_in[4];
  const float* Wa2    = (const float*)d_in[5];
  const float* ba2    = (const float*)d_in[6];
  const float* Wg1    = (const float*)d_in[7];
  const float* bg1    = (const float*)d_in[8];
  const float* Wg2    = (const float*)d_in[9];
  const float* bg2    = (const float*)d_in[10];
  const float* W_ih   = (const float*)d_in[11];
  const float* W_hh   = (const float*)d_in[12];
  const float* b_ih   = (const float*)d_in[13];
  const float* b_hh   = (const float*)d_in[14];
  const float* Wo     = (const float*)d_in[15];
  const float* bo     = (const float*)d_in[16];
  const int* positions= (const int*)d_in[17];
  const int* step     = (const int*)d_in[18];
  float* out = (float*)d_out;  // [0,512) pred | [512] avg_tension | [513..) new_h

  char* w = (char*)d_ws;
  size_t off = 0;
  auto alloc = [&](size_t bytes) { void* p = w + off; off += (bytes + 255) & ~(size_t)255; return p; };
  u16*   hidc    = (u16*)  alloc((size_t)NC * 1024 * 2);
  u16*   outbf   = (u16*)  alloc((size_t)NC * 512 * 2);
  u16*   hpre    = (u16*)  alloc((size_t)NC * 1024 * 2);
  u16*   WgruT   = (u16*)  alloc((size_t)4096 * 1536 * 2);
  u16*   W1catT  = (u16*)  alloc((size_t)256 * 1024 * 2);
  u16*   W2catT  = (u16*)  alloc((size_t)512 * 256 * 2);
  u16*   t1      = (u16*)  alloc((size_t)NC * 256 * 2);
  // zeroed contiguous: bias1 | co | counts | fsums | tension
  float* bias1   = (float*)alloc(256 * 4);
  float* co      = (float*)alloc(512 * 4);
  int*   counts  = (int*)  alloc(16 * 4);
  float* fsums   = (float*)alloc(8 * 3 * 1024 * 4);
  float* tension = (float*)alloc(NC * 4);
  float* bias2   = (float*)alloc(512 * 4);
  float* weights = (float*)alloc(NC * 4);
  float* mean1   = (float*)alloc(1024 * 4);
  float* mean2   = (float*)alloc(1024 * 4);
  float* gop     = (float*)alloc(1024 * 4);
  float* fmean   = (float*)alloc(8 * 1024 * 4);
  float* scal    = (float*)alloc(8 * 4);

  (void)hipMemsetAsync(bias1, 0, 1024 + 2048 + 256 + 98304 + 65536, stream);

  prep_small<<<130, 256, 0, stream>>>(Wa1, Wg1, x, ba1, bg1, bias1, ba2, bg2, bias2,
                                      positions, counts);
  prep_cvt<<<2048, 256, 0, stream>>>(hid, hidc);
  prep_packT<<<1248, 256, 0, stream>>>(W_ih, W_hh, WgruT, Wa1, Wg1, W1catT,
                                       Wa2, Wg2, W2catT);

  // t1 = relu(h @ W1 + bias1)   M=16384 K=1024 N=256
  gemm_bt<<<dim3(128, 2), 256, 0, stream>>>(hidc, 1024, W1catT, 1024, t1, 256,
                                            bias1, 1, 1024, nullptr);
  // output = t1 @ [Wa2;-Wg2] + (ba2-bg2); fused tension
  gemm_bt<<<dim3(128, 4), 256, 0, stream>>>(t1, 256, W2catT, 256, outbf, 512,
                                            bias2, 3, 256, tension);

  // fused GRU (128x64 tiles, 2048 blocks, 256 threads, 4 blocks/CU)
  gemm_gru<<<dim3(128, 16), 256, 0, stream>>>(outbf, hidc, WgruT, W_ih, b_ih, b_hh,
                                              wealth, tension, hpre);

  stats_kernel<<<dim3(8, 8, 8), 256, 0, stream>>>(hpre, positions, fsums);
  derive_kernel<<<1, 1024, 0, stream>>>(fsums, counts, mean1, mean2, fmean, gop, scal);
  finalize_kernel<<<2048, 256, 0, stream>>>(hpre, positions, step, mean1, mean2, fmean, gop,
                                            scal, out);

  softmax_kernel<<<1, 1024, 0, stream>>>(tension, weights, out);
  wsum_kernel<<<128, 256, 0, stream>>>(weights, outbf, co);
  pred_kernel<<<2, 256, 0, stream>>>(co, Wo, bo, out);

  (void)in_sizes; (void)n_in; (void)out_size; (void)ws_size;
}

// Round 10
// 588.589 us; speedup vs baseline: 2.4331x; 2.4331x over previous
//
#include <hip/hip_runtime.h>
#include <stdint.h>

typedef unsigned short u16;
typedef __bf16 bf16x8 __attribute__((ext_vector_type(8)));
typedef float f32x4 __attribute__((ext_vector_type(4)));

// f32 inputs/outputs (verified R2). GEMMs run bf16 MFMA (absmax 0.0156 << 0.05).
// R4: compile-time acc idx / swizzled LDS / occupancy cliffs at 64/128/256 VGPR.
// R5: counted-vmcnt graft on 2-barrier loop = null (regime gate).
// R6: m201-style BK=64 dbuf + counted vmcnt: gemm_gru 209.6->185.8us.
// R7: 2 independent 256-thr blocks/CU: gemm_gru 170.6us.
// R13: BK=32 packed-LDS 40KB (4 blk/CU goal) but __launch_bounds__(256,4) forced
//     VGPR=64 -> 128-VGPR acc SPILLED (WRITE 2.8GB, 1020us). Logic verified correct.
// R14: same kernel, bounds (256,2) — allocator free to take the 128-VGPR tier;
//     LDS 40KB still admits 4 blocks/CU. One-token fix of the R13 spill.

__device__ __forceinline__ float bf2f(unsigned u) { return __uint_as_float(u << 16); }
__device__ __forceinline__ u16 f2bf(float f) {
  unsigned x = __float_as_uint(f);
  unsigned r = x + 0x7fffu + ((x >> 16) & 1u);
  return (u16)(r >> 16);
}
__device__ __forceinline__ unsigned pack2(float a, float b) {
  return (unsigned)f2bf(a) | ((unsigned)f2bf(b) << 16);
}
__device__ __forceinline__ float sigm(float x) { return 1.f / (1.f + __expf(-x)); }
__device__ __forceinline__ float fast_tanh(float x) {
  float e = __expf(2.f * x);
  return 1.f - 2.f / (e + 1.f);
}

#define AS1(p) ((const __attribute__((address_space(1))) void*)(p))
#define AS3(p) ((__attribute__((address_space(3))) void*)(p))

#define NC 16384

// =====================================================================
// prep_cvt: hid f32 -> bf16, 2048 blocks x 256 thr, 8 chunks/thread.
// =====================================================================
__global__ __launch_bounds__(256) void prep_cvt(const float* __restrict__ hid,
                                                u16* __restrict__ hidc) {
  int b = blockIdx.x, t = threadIdx.x;
  const float4* src = (const float4*)hid;
  uint2* dst = (uint2*)hidc;
#pragma unroll
  for (int c = 0; c < 8; ++c) {
    float4 v = src[(size_t)(b + c * 2048) * 256 + t];
    uint2 o; o.x = pack2(v.x, v.y); o.y = pack2(v.z, v.w);
    dst[(size_t)(b + c * 2048) * 256 + t] = o;
  }
}

// =====================================================================
// prep_packT: weight transposes, 1248 blocks.
// =====================================================================
__device__ __forceinline__ void packT_body(
    const float* __restrict__ src, int sld, int srow0,
    u16* __restrict__ dst, int dld, int drow0, int koff,
    int remapThresh, int remapAdd, float sgn, int bx, int by,
    float (*tile)[65], int t) {
  const int k0 = by * 64, c0 = bx * 64;
  const int tx = t & 15, ty = t >> 4;
#pragma unroll
  for (int p = 0; p < 4; ++p) {
    int r = ty + p * 16;
    float4 v = *reinterpret_cast<const float4*>(&src[(size_t)(srow0 + k0 + r) * sld + c0 + tx * 4]);
    tile[tx * 4 + 0][r] = v.x;
    tile[tx * 4 + 1][r] = v.y;
    tile[tx * 4 + 2][r] = v.z;
    tile[tx * 4 + 3][r] = v.w;
  }
  __syncthreads();
  const int cl = t >> 2;
  const int kb = (t & 3) * 16;
  int col = c0 + cl;
  int row = drow0 + col + ((col >= remapThresh) ? remapAdd : 0);
  union { u16 o[16]; uint4 v[2]; } u;
#pragma unroll
  for (int e = 0; e < 16; ++e) u.o[e] = f2bf(sgn * tile[cl][kb + e]);
  uint4* d = reinterpret_cast<uint4*>(&dst[(size_t)row * dld + koff + k0 + kb]);
  d[0] = u.v[0]; d[1] = u.v[1];
}

__global__ __launch_bounds__(256) void prep_packT(
    const float* __restrict__ W_ih, const float* __restrict__ W_hh, u16* __restrict__ WgruT,
    const float* __restrict__ Wa1, const float* __restrict__ Wg1, u16* __restrict__ W1catT,
    const float* __restrict__ Wa2, const float* __restrict__ Wg2, u16* __restrict__ W2catT) {
  __shared__ float tile[64][65];
  int b = blockIdx.x, t = threadIdx.x;
  if (b < 768) {  // W_hh (1024x3072) -> WgruT cols 512..; col>=2048 remaps +1024
    packT_body(W_hh, 3072, 0, WgruT, 1536, 0, 512, 2048, 1024, 1.f, b % 48, b / 48, tile, t);
    return;
  }
  b -= 768;
  if (b < 384) {  // W_ih rows 0..511 -> WgruT cols 0..511
    packT_body(W_ih, 3072, 0, WgruT, 1536, 0, 0, 1 << 30, 0, 1.f, b % 48, b / 48, tile, t);
    return;
  }
  b -= 384;
  if (b < 32) { packT_body(Wa1, 128, 512, W1catT, 1024, 0, 0, 1 << 30, 0, 1.f, b % 2, b / 2, tile, t); return; }
  b -= 32;
  if (b < 32) { packT_body(Wg1, 128, 512, W1catT, 1024, 128, 0, 1 << 30, 0, 1.f, b % 2, b / 2, tile, t); return; }
  b -= 32;
  if (b < 16) { packT_body(Wa2, 512, 0, W2catT, 256, 0, 0, 1 << 30, 0, 1.f, b % 8, b / 8, tile, t); return; }
  b -= 16;
  { packT_body(Wg2, 512, 0, W2catT, 256, 0, 128, 1 << 30, 0, -1.f, b % 8, b / 8, tile, t); }
}

// =====================================================================
// prep_small: bias1 (64 blocks, 8 unrolled k each) | bias2 (2) | counts (64).
// =====================================================================
__global__ __launch_bounds__(256) void prep_small(
    const float* __restrict__ Wa1, const float* __restrict__ Wg1,
    const float* __restrict__ x, const float* __restrict__ ba1, const float* __restrict__ bg1,
    float* __restrict__ bias1, const float* __restrict__ ba2, const float* __restrict__ bg2,
    float* __restrict__ bias2, const int* __restrict__ positions, int* __restrict__ counts) {
  int b = blockIdx.x, t = threadIdx.x;
  if (b < 64) {  // bias1: k-split 8 per block, unrolled independent loads
    const float* W = (t < 128) ? Wa1 : Wg1;
    int cc = t & 127;
    int k0 = b * 8;
    float wv[8], xv[8];
#pragma unroll
    for (int j = 0; j < 8; ++j) {
      xv[j] = x[k0 + j];
      wv[j] = W[(size_t)(k0 + j) * 128 + cc];
    }
    float acc = 0.f;
#pragma unroll
    for (int j = 0; j < 8; ++j) acc += xv[j] * wv[j];
    if (b == 0) acc += (t < 128) ? ba1[cc] : bg1[cc];
    atomicAdd(&bias1[t], acc);
    return;
  }
  b -= 64;
  if (b < 2) { int n = b * 256 + t; bias2[n] = ba2[n] - bg2[n]; return; }
  b -= 2;
  {
    int i = b * 256 + t;
    int p = positions[i], f = i >> 11;
    if (p > 0) atomicAdd(&counts[f * 2], 1);
    else if (p < 0) atomicAdd(&counts[f * 2 + 1], 1);
  }
}

// =====================================================================
// bf16 MFMA GEMM, 128x128, BK=32, XOR-swizzled LDS (slot = q ^ ((row>>1)&3)).
// Triple-buffered, depth-2 prefetch, counted vmcnt. epi 1: +bias,relu ;
// epi 3: +bias + fused per-row sum-of-squares -> tension.
// =====================================================================
__global__ __launch_bounds__(256) void gemm_bt(
    const u16* __restrict__ A, int lda,
    const u16* __restrict__ Bt, int ldb,
    u16* __restrict__ C, int ldc,
    const float* __restrict__ bias, int epi, int K,
    float* __restrict__ tension) {
  __shared__ __align__(16) u16 As[3][128 * 32];
  __shared__ __align__(16) u16 Bs[3][128 * 32];
  const int tid = threadIdx.x;
  const int m0 = blockIdx.x * 128;
  const int n0 = blockIdx.y * 128;
  f32x4 acc[4][4] = {};
  const int lane = tid & 63;
  const int w = tid >> 6;
  const int mw = (w & 1) * 64, nw = (w >> 1) * 64;
  const int fr = lane & 15;
  const int q = lane >> 4;
  const int ar0 = tid >> 2;                     // rows 0..63 (chunk tid), +64 for chunk tid+256
  const int ag = ((tid & 3) ^ ((ar0 >> 1) & 3)) * 8;  // (row+64)>>1 keeps same &3 -> ag reused

  const u16* aB0 = A + (size_t)(m0 + ar0) * lda + ag;
  const u16* aB1 = A + (size_t)(m0 + ar0 + 64) * lda + ag;
  const u16* bB0 = Bt + (size_t)(n0 + ar0) * ldb + ag;
  const u16* bB1 = Bt + (size_t)(n0 + ar0 + 64) * ldb + ag;

  auto stage = [&](int kk, int buf) {
    __builtin_amdgcn_global_load_lds(AS1(aB0 + kk), AS3(&As[buf][tid * 8]), 16, 0, 0);
    __builtin_amdgcn_global_load_lds(AS1(aB1 + kk), AS3(&As[buf][(tid + 256) * 8]), 16, 0, 0);
    __builtin_amdgcn_global_load_lds(AS1(bB0 + kk), AS3(&Bs[buf][tid * 8]), 16, 0, 0);
    __builtin_amdgcn_global_load_lds(AS1(bB1 + kk), AS3(&Bs[buf][(tid + 256) * 8]), 16, 0, 0);
  };

  const int NT = K >> 5;   // >= 8 for all calls
  stage(0, 0);
  stage(32, 1);
  int cur = 0, nxt = 1, nx2 = 2;
#pragma unroll 1
  for (int t = 0; t < NT; ++t) {
    if (t + 2 < NT) stage((t + 2) * 32, nx2);
    const int rem = NT - 1 - t;  // tiles newer than t in flight
    if (rem >= 2)      asm volatile("s_waitcnt vmcnt(8)" ::: "memory");
    else if (rem == 1) asm volatile("s_waitcnt vmcnt(4)" ::: "memory");
    else               asm volatile("s_waitcnt vmcnt(0)" ::: "memory");
    __builtin_amdgcn_s_barrier();          // tile t fully in LDS (all waves)
    asm volatile("" ::: "memory");
    bf16x8 af[4], bfv[4];
#pragma unroll
    for (int mt = 0; mt < 4; ++mt) {
      int r = mw + mt * 16 + fr;
      af[mt] = *reinterpret_cast<const bf16x8*>(&As[cur][r * 32 + ((q ^ ((r >> 1) & 3)) * 8)]);
    }
#pragma unroll
    for (int nt = 0; nt < 4; ++nt) {
      int r = nw + nt * 16 + fr;
      bfv[nt] = *reinterpret_cast<const bf16x8*>(&Bs[cur][r * 32 + ((q ^ ((r >> 1) & 3)) * 8)]);
    }
    __builtin_amdgcn_s_setprio(1);
#pragma unroll
    for (int mt = 0; mt < 4; ++mt)
#pragma unroll
      for (int nt = 0; nt < 4; ++nt)
        acc[mt][nt] = __builtin_amdgcn_mfma_f32_16x16x32_bf16(af[mt], bfv[nt], acc[mt][nt], 0, 0, 0);
    __builtin_amdgcn_s_setprio(0);
    asm volatile("s_waitcnt lgkmcnt(0)" ::: "memory");  // my ds_reads retired
    __builtin_amdgcn_s_barrier();          // buf[cur] safe to overwrite at t+1
    int tmp = cur; cur = nxt; nxt = nx2; nx2 = tmp;
  }
  const int rq = q * 4;  // D: col=lane&15, row=rq+reg [m89]
#pragma unroll
  for (int mt = 0; mt < 4; ++mt) {
    float srow[4] = {0.f, 0.f, 0.f, 0.f};
#pragma unroll
    for (int nt = 0; nt < 4; ++nt) {
      int col = n0 + nw + nt * 16 + fr;
      f32x4 v = acc[mt][nt];
#pragma unroll
      for (int r = 0; r < 4; ++r) {
        int row = m0 + mw + mt * 16 + rq + r;
        float val = v[r] + bias[col];
        if (epi == 1) val = val > 0.f ? val : 0.f;
        else srow[r] += val * val;
        C[(size_t)row * ldc + col] = f2bf(val);
      }
    }
    if (epi == 3) {
#pragma unroll
      for (int r = 0; r < 4; ++r) {
        float s = srow[r];
        s += __shfl_xor(s, 1, 16); s += __shfl_xor(s, 2, 16);
        s += __shfl_xor(s, 4, 16); s += __shfl_xor(s, 8, 16);
        if (fr == 0) atomicAdd(&tension[m0 + mw + mt * 16 + rq + r], s);
      }
    }
  }
}

// =====================================================================
// R14 fused GRU (= R13 logic, bounds (256,2)). 256 threads / 4 waves; block
// tile 128 rows x 64 j x 4 reg; BK=32; wave = 64 rows x 32 j x 4 reg
// (acc[4][4][2] = 128 VGPR). LDS 40KB: As[2][64][64] (row r' packs A-rows
// {r', r'+64}), Bs[2][3][32][64] (row r' packs B-rows {r', r'+32}).
// 8 swizzled 16B slots/row, s_phys = sidx ^ (r'&7); 128B row stride keeps the
// proven conflict-free profile. 5 gloads/thread/tile, depth-2, vmcnt(5).
// Per K-tile: 10 ds_read -> lgkm0 -> bar -> STAGE(t+2) -> 24 MFMA -> vmcnt(5) -> bar.
// Tiles 0..15: A=outbf, reg3=gi_n(rows 2048+); 16..47: A=hidc, reg3=gh_n(3072+).
// =====================================================================
__global__ __launch_bounds__(256, 2) void gemm_gru(
    const u16* __restrict__ outbf, const u16* __restrict__ hidc,
    const u16* __restrict__ WgruT,
    const float* __restrict__ W_ihf, const float* __restrict__ bihf,
    const float* __restrict__ bhhf, const float* __restrict__ wealthf,
    const float* __restrict__ tension, u16* __restrict__ hpre) {
  __shared__ __align__(16) u16 As[2][64 * 64];
  __shared__ __align__(16) u16 Bs[2][3][32 * 64];
  const int tid = threadIdx.x;
  const int m0 = blockIdx.x * 128;
  const int j0 = blockIdx.y * 64;
  f32x4 acc[4][4][2] = {};  // [region][mt][nt]
  const int lane = tid & 63;
  const int w = tid >> 6;
  const int mw = (w & 1) * 64, jw = (w >> 1) * 32;
  const int fr = lane & 15;
  const int q = lane >> 4;
  const int f7 = fr & 7;
  // fragment slot offsets (u16): s_phys = (q + half*4) ^ f7 ; half is wave-fixed
  const int skA = ((q + (w & 1) * 4) ^ f7) * 8;
  const int skB = ((q + (w >> 1) * 4) ^ f7) * 8;
  // staging: chunk tid -> LDS 16B chunk tid; stored sidx = (tid&7) ^ ((tid>>3)&7)
  const int rl = tid >> 3;                    // LDS row 0..31
  const int sidx = (tid & 7) ^ (rl & 7);
  const int kcol = (sidx & 3) * 8;
  const int ah = (sidx >= 4) ? 64 : 0;        // A packs rows {r', r'+64}
  const int bh = (sidx >= 4) ? 32 : 0;        // B packs rows {j', j'+32}
  const size_t aOut1 = (size_t)(m0 + rl + ah) * 512 + kcol;   // load1: LDS rows 0..31
  const size_t aOut2 = aOut1 + (size_t)32 * 512;              // load2: LDS rows 32..63
  const size_t aHid1 = (size_t)(m0 + rl + ah) * 1024 + kcol;
  const size_t aHid2 = aHid1 + (size_t)32 * 1024;
  const size_t bBase = (size_t)(j0 + rl + bh) * 1536 + kcol;

// sA keeps the untaken branch's constant-folded A offset non-negative (R11).
#define STAGE(S, BUF)                                                                              \
  {                                                                                                \
    const int sA = (S) < 16 ? (S) : (S) - 16;                                                      \
    const size_t kOA = (size_t)sA * 32;                                                            \
    const size_t kOB = (size_t)(S) * 32;                                                           \
    if ((S) < 16) {                                                                                \
      __builtin_amdgcn_global_load_lds(AS1(outbf + aOut1 + kOA), AS3(&As[BUF][tid * 8]), 16, 0, 0);\
      __builtin_amdgcn_global_load_lds(AS1(outbf + aOut2 + kOA),                                   \
                                       AS3(&As[BUF][2048 + tid * 8]), 16, 0, 0);                   \
    } else {                                                                                       \
      __builtin_amdgcn_global_load_lds(AS1(hidc + aHid1 + kOA), AS3(&As[BUF][tid * 8]), 16, 0, 0); \
      __builtin_amdgcn_global_load_lds(AS1(hidc + aHid2 + kOA),                                    \
                                       AS3(&As[BUF][2048 + tid * 8]), 16, 0, 0);                   \
    }                                                                                              \
    const u16* bp = WgruT + bBase + kOB;                                                           \
    __builtin_amdgcn_global_load_lds(AS1(bp), AS3(&Bs[BUF][0][tid * 8]), 16, 0, 0);                \
    __builtin_amdgcn_global_load_lds(AS1(bp + (size_t)1024 * 1536),                                \
                                     AS3(&Bs[BUF][1][tid * 8]), 16, 0, 0);                         \
    __builtin_amdgcn_global_load_lds(AS1(bp + (size_t)((S) < 16 ? 2048 : 3072) * 1536),            \
                                     AS3(&Bs[BUF][2][tid * 8]), 16, 0, 0);                         \
  }

#define GRU_STEP(T, REG3, CUR)                                                                     \
  {                                                                                                \
    bf16x8 af[4], b0v[2], b1v[2], b2v[2];                                                          \
    _Pragma("unroll") for (int mt = 0; mt < 4; ++mt)                                               \
        af[mt] = *reinterpret_cast<const bf16x8*>(&As[CUR][(mt * 16 + fr) * 64 + skA]);            \
    _Pragma("unroll") for (int nt = 0; nt < 2; ++nt) {                                             \
      int rj = (nt * 16 + fr) * 64 + skB;                                                          \
      b0v[nt] = *reinterpret_cast<const bf16x8*>(&Bs[CUR][0][rj]);                                 \
      b1v[nt] = *reinterpret_cast<const bf16x8*>(&Bs[CUR][1][rj]);                                 \
      b2v[nt] = *reinterpret_cast<const bf16x8*>(&Bs[CUR][2][rj]);                                 \
    }                                                                                              \
    asm volatile("s_waitcnt lgkmcnt(0)" ::: "memory");                                             \
    __builtin_amdgcn_s_barrier();                                                                  \
    asm volatile("" ::: "memory");                                                                 \
    if ((T) + 2 < 48) { STAGE((T) + 2, CUR) }                                                      \
    __builtin_amdgcn_s_setprio(1);                                                                 \
    _Pragma("unroll") for (int mt = 0; mt < 4; ++mt)                                               \
        _Pragma("unroll") for (int nt = 0; nt < 2; ++nt) {                                         \
      acc[0][mt][nt] = __builtin_amdgcn_mfma_f32_16x16x32_bf16(af[mt], b0v[nt], acc[0][mt][nt], 0, 0, 0); \
      acc[1][mt][nt] = __builtin_amdgcn_mfma_f32_16x16x32_bf16(af[mt], b1v[nt], acc[1][mt][nt], 0, 0, 0); \
      acc[REG3][mt][nt] = __builtin_amdgcn_mfma_f32_16x16x32_bf16(af[mt], b2v[nt], acc[REG3][mt][nt], 0, 0, 0); \
    }                                                                                              \
    __builtin_amdgcn_s_setprio(0);                                                                 \
    if ((T) + 2 < 48)      { asm volatile("s_waitcnt vmcnt(5)" ::: "memory"); }                    \
    else if ((T) + 1 < 48) { asm volatile("s_waitcnt vmcnt(0)" ::: "memory"); }                    \
    __builtin_amdgcn_s_barrier();                                                                  \
    asm volatile("" ::: "memory");                                                                 \
  }

  STAGE(0, 0)
  STAGE(1, 1)
  asm volatile("s_waitcnt vmcnt(5)" ::: "memory");
  __builtin_amdgcn_s_barrier();
  asm volatile("" ::: "memory");
#pragma unroll 1
  for (int T = 0; T < 16; T += 2) {   // tiles 0..15: reg3 = gi_n
    GRU_STEP(T, 2, 0)
    GRU_STEP(T + 1, 2, 1)
  }
#pragma unroll 1
  for (int T = 16; T < 48; T += 2) {  // tiles 16..47: reg3 = gh_n
    GRU_STEP(T, 3, 0)
    GRU_STEP(T + 1, 3, 1)
  }
#undef GRU_STEP
#undef STAGE

  // epilogue: D col=lane&15, row=(lane>>4)*4+reg [m89]
  const int rq = q * 4;
  const float* wt = W_ihf + (size_t)512 * 3072;  // tension row
  float wtr[2], wtz[2], wtn[2], bir[2], biz[2], bin_[2], bhr_[2], bhz_[2], bhn_[2];
#pragma unroll
  for (int nt = 0; nt < 2; ++nt) {
    int j = j0 + jw + nt * 16 + fr;
    wtr[nt] = wt[j]; wtz[nt] = wt[1024 + j]; wtn[nt] = wt[2048 + j];
    bir[nt] = bihf[j]; biz[nt] = bihf[1024 + j]; bin_[nt] = bihf[2048 + j];
    bhr_[nt] = bhhf[j]; bhz_[nt] = bhhf[1024 + j]; bhn_[nt] = bhhf[2048 + j];
  }
#pragma unroll
  for (int mt = 0; mt < 4; ++mt) {
#pragma unroll
    for (int rr = 0; rr < 4; ++rr) {
      int row = m0 + mw + mt * 16 + rq + rr;
      float tv = tension[row] * (1.f / 512.f);
      float wl = fminf(fmaxf(wealthf[row], 0.1f), 2.0f);
      float mod = 0.9f + 0.1f * wl;
#pragma unroll
      for (int nt = 0; nt < 2; ++nt) {
        int j = j0 + jw + nt * 16 + fr;
        float r = sigm(acc[0][mt][nt][rr] + tv * wtr[nt] + bir[nt] + bhr_[nt]);
        float z = sigm(acc[1][mt][nt][rr] + tv * wtz[nt] + biz[nt] + bhz_[nt]);
        float n = fast_tanh(acc[2][mt][nt][rr] + tv * wtn[nt] + bin_[nt]
                            + r * (acc[3][mt][nt][rr] + bhn_[nt]));
        float h = bf2f(hidc[(size_t)row * 1024 + j]);
        float h2 = (1.f - z) * n + z * h;
        h2 = fminf(fmaxf(h2 * mod, -10.f), 10.f);
        hpre[(size_t)row * 1024 + j] = f2bf(h2);
      }
    }
  }
}

// =====================================================================
__global__ void stats_kernel(const u16* __restrict__ hpre, const int* __restrict__ positions,
                             float* __restrict__ fsums) {
  int cc = blockIdx.x, f = blockIdx.y, z = blockIdx.z, t = threadIdx.x;
  int col = cc * 128 + (t & 127);
  int half = t >> 7;
  float st = 0, sp = 0, sm = 0;
  for (int it = 0; it < 128; ++it) {
    int row = (f << 11) + ((z * 128 + it) << 1) + half;
    int p = positions[row];
    float v = bf2f(hpre[(size_t)row * 1024 + col]);
    st += v;
    if (p > 0) sp += v;
    if (p < 0) sm += v;
  }
  atomicAdd(&fsums[(f * 3 + 0) * 1024 + col], st);
  atomicAdd(&fsums[(f * 3 + 1) * 1024 + col], sp);
  atomicAdd(&fsums[(f * 3 + 2) * 1024 + col], sm);
}

__global__ void derive_kernel(const float* __restrict__ fsums, const int* __restrict__ counts,
                              float* __restrict__ mean1, float* __restrict__ mean2,
                              float* __restrict__ fmean, float* __restrict__ gop,
                              float* __restrict__ scal) {
  int c = threadIdx.x;  // 1024
  int cnt1 = 0, cnt2 = 0, cf1[8], cf2[8];
#pragma unroll
  for (int f = 0; f < 8; ++f) {
    cf1[f] = counts[f * 2]; cf2[f] = counts[f * 2 + 1];
    cnt1 += cf1[f]; cnt2 += cf2[f];
  }
  float s1 = 0, s2 = 0;
#pragma unroll
  for (int f = 0; f < 8; ++f) { s1 += fsums[(f * 3 + 1) * 1024 + c]; s2 += fsums[(f * 3 + 2) * 1024 + c]; }
  float m1 = s1 / (float)(cnt1 > 1 ? cnt1 : 1);
  float m2 = s2 / (float)(cnt2 > 1 ? cnt2 : 1);
  float a1 = (cnt1 >= 2) ? 0.1f : 0.f;
  float a2 = (cnt2 >= 2) ? 0.1f : 0.f;
  float g = 0;
#pragma unroll
  for (int f = 0; f < 8; ++f) {
    float fm = (fsums[(f * 3) * 1024 + c]
                + a1 * ((float)cf1[f] * m1 - fsums[(f * 3 + 1) * 1024 + c])
                + a2 * ((float)cf2[f] * m2 - fsums[(f * 3 + 2) * 1024 + c])) * (1.f / 2048.f);
    fmean[f * 1024 + c] = fm;
    g += fm;
  }
  gop[c] = g * 0.125f;
  mean1[c] = m1; mean2[c] = m2;
  if (c == 0) { scal[0] = a1; scal[1] = a2; }
}

// 2048 blocks x 256 thr; block handles 8 rows x 1024 cols (4 col-slices).
__global__ void finalize_kernel(const u16* __restrict__ hpre, const int* __restrict__ positions,
                                const int* __restrict__ step, const float* __restrict__ mean1,
                                const float* __restrict__ mean2, const float* __restrict__ fmean,
                                const float* __restrict__ gop, const float* __restrict__ scal,
                                float* __restrict__ out) {
  int t = threadIdx.x;
  int r0 = blockIdx.x * 8;
  float s0 = scal[0], s1 = scal[1];
  bool step5 = step[0] > 5;
#pragma unroll 2
  for (int rr = 0; rr < 8; ++rr) {
    int row = r0 + rr;
    int p = positions[row];
    float w1 = (p > 0) ? s0 : 0.f;
    float w2 = (p < 0) ? s1 : 0.f;
    int f = row >> 11, qq = row & 2047;
    bool deb = step5 && (qq < 512);
    const u16* hrow = hpre + (size_t)row * 1024;
    const float* fmp = fmean + f * 1024;
    float* orow = out + 513 + (size_t)row * 1024;
#pragma unroll
    for (int e = 0; e < 4; ++e) {
      int c = e * 256 + t;
      float h = bf2f(hrow[c]);
      float hgs = h + w1 * (mean1[c] - h) + w2 * (mean2[c] - h);
      float hfs = 0.85f * hgs + 0.15f * fmp[c];
      orow[c] = deb ? (0.85f * hfs + 0.15f * gop[c]) : hfs;
    }
  }
}

__global__ void softmax_kernel(const float* __restrict__ tension, float* __restrict__ weights,
                               float* __restrict__ out) {
  __shared__ float red[1024];
  int t = threadIdx.x;
  float tv[16], mx = -1e30f, sumt = 0.f;
#pragma unroll
  for (int k = 0; k < 16; ++k) {
    tv[k] = tension[t + k * 1024] * (1.f / 512.f);
    mx = fmaxf(mx, tv[k]); sumt += tv[k];
  }
  red[t] = mx; __syncthreads();
  for (int s = 512; s > 0; s >>= 1) { if (t < s) red[t] = fmaxf(red[t], red[t + s]); __syncthreads(); }
  float m = red[0]; __syncthreads();
  red[t] = sumt; __syncthreads();
  for (int s = 512; s > 0; s >>= 1) { if (t < s) red[t] += red[t + s]; __syncthreads(); }
  float tot = red[0]; __syncthreads();
  float ev[16], se = 0.f;
#pragma unroll
  for (int k = 0; k < 16; ++k) { ev[k] = __expf(tv[k] - m); se += ev[k]; }
  red[t] = se; __syncthreads();
  for (int s = 512; s > 0; s >>= 1) { if (t < s) red[t] += red[t + s]; __syncthreads(); }
  float invS = 1.f / red[0];
#pragma unroll
  for (int k = 0; k < 16; ++k) weights[t + k * 1024] = ev[k] * invS;
  if (t == 0) out[512] = tot * (1.f / 16384.f);
}

__global__ void wsum_kernel(const float* __restrict__ weights, const u16* __restrict__ outbf,
                            float* __restrict__ co) {
  int b = blockIdx.x, t = threadIdx.x;
  int c = t * 2;
  float a0 = 0.f, a1 = 0.f;
  int i0 = b * 128;
  for (int i = i0; i < i0 + 128; ++i) {
    float w = weights[i];
    unsigned v = *reinterpret_cast<const unsigned*>(outbf + (size_t)i * 512 + c);
    a0 += w * bf2f(v & 0xffff);
    a1 += w * bf2f(v >> 16);
  }
  atomicAdd(&co[c], a0);
  atomicAdd(&co[c + 1], a1);
}

__global__ void pred_kernel(const float* __restrict__ co, const float* __restrict__ Wof,
                            const float* __restrict__ bof, float* __restrict__ out) {
  __shared__ float cs[512];
  int t = threadIdx.x, n = blockIdx.x * 256 + t;
  cs[t] = co[t]; cs[t + 256] = co[t + 256];
  __syncthreads();
  float acc = bof[n];
  for (int ck = 0; ck < 512; ++ck) acc += cs[ck] * Wof[(size_t)ck * 512 + n];
  out[n] = acc;
}

// =====================================================================
extern "C" void kernel_launch(void* const* d_in, const int* in_sizes, int n_in,
                              void* d_out, int out_size, void* d_ws, size_t ws_size,
                              hipStream_t stream) {
  const float* x      = (const float*)d_in[0];
  const float* hid    = (const float*)d_in[1];
  const float* wealth = (const float*)d_in[2];
  const float* Wa1    = (const float*)d_in[3];
  const float* ba1    = (const float*)d_in[4];
  const float* Wa2    = (const float*)d_in[5];
  const float* ba2    = (const float*)d_in[6];
  const float* Wg1    = (const float*)d_in[7];
  const float* bg1    = (const float*)d_in[8];
  const float* Wg2    = (const float*)d_in[9];
  const float* bg2    = (const float*)d_in[10];
  const float* W_ih   = (const float*)d_in[11];
  const float* W_hh   = (const float*)d_in[12];
  const float* b_ih   = (const float*)d_in[13];
  const float* b_hh   = (const float*)d_in[14];
  const float* Wo     = (const float*)d_in[15];
  const float* bo     = (const float*)d_in[16];
  const int* positions= (const int*)d_in[17];
  const int* step     = (const int*)d_in[18];
  float* out = (float*)d_out;  // [0,512) pred | [512] avg_tension | [513..) new_h

  char* w = (char*)d_ws;
  size_t off = 0;
  auto alloc = [&](size_t bytes) { void* p = w + off; off += (bytes + 255) & ~(size_t)255; return p; };
  u16*   hidc    = (u16*)  alloc((size_t)NC * 1024 * 2);
  u16*   outbf   = (u16*)  alloc((size_t)NC * 512 * 2);
  u16*   hpre    = (u16*)  alloc((size_t)NC * 1024 * 2);
  u16*   WgruT   = (u16*)  alloc((size_t)4096 * 1536 * 2);
  u16*   W1catT  = (u16*)  alloc((size_t)256 * 1024 * 2);
  u16*   W2catT  = (u16*)  alloc((size_t)512 * 256 * 2);
  u16*   t1      = (u16*)  alloc((size_t)NC * 256 * 2);
  // zeroed contiguous: bias1 | co | counts | fsums | tension
  float* bias1   = (float*)alloc(256 * 4);
  float* co      = (float*)alloc(512 * 4);
  int*   counts  = (int*)  alloc(16 * 4);
  float* fsums   = (float*)alloc(8 * 3 * 1024 * 4);
  float* tension = (float*)alloc(NC * 4);
  float* bias2   = (float*)alloc(512 * 4);
  float* weights = (float*)alloc(NC * 4);
  float* mean1   = (float*)alloc(1024 * 4);
  float* mean2   = (float*)alloc(1024 * 4);
  float* gop     = (float*)alloc(1024 * 4);
  float* fmean   = (float*)alloc(8 * 1024 * 4);
  float* scal    = (float*)alloc(8 * 4);

  (void)hipMemsetAsync(bias1, 0, 1024 + 2048 + 256 + 98304 + 65536, stream);

  prep_small<<<130, 256, 0, stream>>>(Wa1, Wg1, x, ba1, bg1, bias1, ba2, bg2, bias2,
                                      positions, counts);
  prep_cvt<<<2048, 256, 0, stream>>>(hid, hidc);
  prep_packT<<<1248, 256, 0, stream>>>(W_ih, W_hh, WgruT, Wa1, Wg1, W1catT,
                                       Wa2, Wg2, W2catT);

  // t1 = relu(h @ W1 + bias1)   M=16384 K=1024 N=256
  gemm_bt<<<dim3(128, 2), 256, 0, stream>>>(hidc, 1024, W1catT, 1024, t1, 256,
                                            bias1, 1, 1024, nullptr);
  // output = t1 @ [Wa2;-Wg2] + (ba2-bg2); fused tension
  gemm_bt<<<dim3(128, 4), 256, 0, stream>>>(t1, 256, W2catT, 256, outbf, 512,
                                            bias2, 3, 256, tension);

  // fused GRU (128x64 tiles, 2048 blocks, 256 threads, LDS-limit 4 blocks/CU)
  gemm_gru<<<dim3(128, 16), 256, 0, stream>>>(outbf, hidc, WgruT, W_ih, b_ih, b_hh,
                                              wealth, tension, hpre);

  stats_kernel<<<dim3(8, 8, 8), 256, 0, stream>>>(hpre, positions, fsums);
  derive_kernel<<<1, 1024, 0, stream>>>(fsums, counts, mean1, mean2, fmean, gop, scal);
  finalize_kernel<<<2048, 256, 0, stream>>>(hpre, positions, step, mean1, mean2, fmean, gop,
                                            scal, out);

  softmax_kernel<<<1, 1024, 0, stream>>>(tension, weights, out);
  wsum_kernel<<<128, 256, 0, stream>>>(weights, outbf, co);
  pred_kernel<<<2, 256, 0, stream>>>(co, Wo, bo, out);

  (void)in_sizes; (void)n_in; (void)out_size; (void)ws_size;
}

// Round 11
// 564.227 us; speedup vs baseline: 2.5381x; 1.0432x over previous
//
#include <hip/hip_runtime.h>
#include <stdint.h>

typedef unsigned short u16;
typedef __bf16 bf16x8 __attribute__((ext_vector_type(8)));
typedef float f32x4 __attribute__((ext_vector_type(4)));

// f32 inputs/outputs (verified R2). GEMMs run bf16 MFMA (absmax 0.0156 << 0.05).
// R4: compile-time acc idx / swizzled LDS / occupancy cliffs at 64/128/256 VGPR.
// R6: m201-style BK=64 dbuf + counted vmcnt: gemm_gru 209.6->185.8us.
// R7/R12: 2 independent 256-thr blocks/CU (BK=64, 80KB LDS): gemm_gru 170.6us.
// R13: BK=32 + bounds(256,4): acc spilled (VGPR 64, WRITE 2.8GB, 1020us).
// R14: bounds(256,2): no spill but VGPR96+AGPR128=224 regs => STILL 2 blk/CU;
//     48 tiles vs 24 doubled barriers => 195us REGRESSION. Occupancy tier is
//     set by VGPR+AGPR combined; 128-AGPR acc pins 2 blk/CU at this wave tile.
// R15: revert gemm_gru to R12 exact; split into two m-half launches (~85us each)
//     to break its top-5 monopoly and expose the ~400us non-gru pool.

__device__ __forceinline__ float bf2f(unsigned u) { return __uint_as_float(u << 16); }
__device__ __forceinline__ u16 f2bf(float f) {
  unsigned x = __float_as_uint(f);
  unsigned r = x + 0x7fffu + ((x >> 16) & 1u);
  return (u16)(r >> 16);
}
__device__ __forceinline__ unsigned pack2(float a, float b) {
  return (unsigned)f2bf(a) | ((unsigned)f2bf(b) << 16);
}
__device__ __forceinline__ float sigm(float x) { return 1.f / (1.f + __expf(-x)); }
__device__ __forceinline__ float fast_tanh(float x) {
  float e = __expf(2.f * x);
  return 1.f - 2.f / (e + 1.f);
}

#define AS1(p) ((const __attribute__((address_space(1))) void*)(p))
#define AS3(p) ((__attribute__((address_space(3))) void*)(p))

#define NC 16384

// =====================================================================
// prep_cvt: hid f32 -> bf16, 2048 blocks x 256 thr, 8 chunks/thread.
// =====================================================================
__global__ __launch_bounds__(256) void prep_cvt(const float* __restrict__ hid,
                                                u16* __restrict__ hidc) {
  int b = blockIdx.x, t = threadIdx.x;
  const float4* src = (const float4*)hid;
  uint2* dst = (uint2*)hidc;
#pragma unroll
  for (int c = 0; c < 8; ++c) {
    float4 v = src[(size_t)(b + c * 2048) * 256 + t];
    uint2 o; o.x = pack2(v.x, v.y); o.y = pack2(v.z, v.w);
    dst[(size_t)(b + c * 2048) * 256 + t] = o;
  }
}

// =====================================================================
// prep_packT: weight transposes, 1248 blocks.
// =====================================================================
__device__ __forceinline__ void packT_body(
    const float* __restrict__ src, int sld, int srow0,
    u16* __restrict__ dst, int dld, int drow0, int koff,
    int remapThresh, int remapAdd, float sgn, int bx, int by,
    float (*tile)[65], int t) {
  const int k0 = by * 64, c0 = bx * 64;
  const int tx = t & 15, ty = t >> 4;
#pragma unroll
  for (int p = 0; p < 4; ++p) {
    int r = ty + p * 16;
    float4 v = *reinterpret_cast<const float4*>(&src[(size_t)(srow0 + k0 + r) * sld + c0 + tx * 4]);
    tile[tx * 4 + 0][r] = v.x;
    tile[tx * 4 + 1][r] = v.y;
    tile[tx * 4 + 2][r] = v.z;
    tile[tx * 4 + 3][r] = v.w;
  }
  __syncthreads();
  const int cl = t >> 2;
  const int kb = (t & 3) * 16;
  int col = c0 + cl;
  int row = drow0 + col + ((col >= remapThresh) ? remapAdd : 0);
  union { u16 o[16]; uint4 v[2]; } u;
#pragma unroll
  for (int e = 0; e < 16; ++e) u.o[e] = f2bf(sgn * tile[cl][kb + e]);
  uint4* d = reinterpret_cast<uint4*>(&dst[(size_t)row * dld + koff + k0 + kb]);
  d[0] = u.v[0]; d[1] = u.v[1];
}

__global__ __launch_bounds__(256) void prep_packT(
    const float* __restrict__ W_ih, const float* __restrict__ W_hh, u16* __restrict__ WgruT,
    const float* __restrict__ Wa1, const float* __restrict__ Wg1, u16* __restrict__ W1catT,
    const float* __restrict__ Wa2, const float* __restrict__ Wg2, u16* __restrict__ W2catT) {
  __shared__ float tile[64][65];
  int b = blockIdx.x, t = threadIdx.x;
  if (b < 768) {  // W_hh (1024x3072) -> WgruT cols 512..; col>=2048 remaps +1024
    packT_body(W_hh, 3072, 0, WgruT, 1536, 0, 512, 2048, 1024, 1.f, b % 48, b / 48, tile, t);
    return;
  }
  b -= 768;
  if (b < 384) {  // W_ih rows 0..511 -> WgruT cols 0..511
    packT_body(W_ih, 3072, 0, WgruT, 1536, 0, 0, 1 << 30, 0, 1.f, b % 48, b / 48, tile, t);
    return;
  }
  b -= 384;
  if (b < 32) { packT_body(Wa1, 128, 512, W1catT, 1024, 0, 0, 1 << 30, 0, 1.f, b % 2, b / 2, tile, t); return; }
  b -= 32;
  if (b < 32) { packT_body(Wg1, 128, 512, W1catT, 1024, 128, 0, 1 << 30, 0, 1.f, b % 2, b / 2, tile, t); return; }
  b -= 32;
  if (b < 16) { packT_body(Wa2, 512, 0, W2catT, 256, 0, 0, 1 << 30, 0, 1.f, b % 8, b / 8, tile, t); return; }
  b -= 16;
  { packT_body(Wg2, 512, 0, W2catT, 256, 0, 128, 1 << 30, 0, -1.f, b % 8, b / 8, tile, t); }
}

// =====================================================================
// prep_small: bias1 (64 blocks, 8 unrolled k each) | bias2 (2) | counts (64).
// =====================================================================
__global__ __launch_bounds__(256) void prep_small(
    const float* __restrict__ Wa1, const float* __restrict__ Wg1,
    const float* __restrict__ x, const float* __restrict__ ba1, const float* __restrict__ bg1,
    float* __restrict__ bias1, const float* __restrict__ ba2, const float* __restrict__ bg2,
    float* __restrict__ bias2, const int* __restrict__ positions, int* __restrict__ counts) {
  int b = blockIdx.x, t = threadIdx.x;
  if (b < 64) {  // bias1: k-split 8 per block, unrolled independent loads
    const float* W = (t < 128) ? Wa1 : Wg1;
    int cc = t & 127;
    int k0 = b * 8;
    float wv[8], xv[8];
#pragma unroll
    for (int j = 0; j < 8; ++j) {
      xv[j] = x[k0 + j];
      wv[j] = W[(size_t)(k0 + j) * 128 + cc];
    }
    float acc = 0.f;
#pragma unroll
    for (int j = 0; j < 8; ++j) acc += xv[j] * wv[j];
    if (b == 0) acc += (t < 128) ? ba1[cc] : bg1[cc];
    atomicAdd(&bias1[t], acc);
    return;
  }
  b -= 64;
  if (b < 2) { int n = b * 256 + t; bias2[n] = ba2[n] - bg2[n]; return; }
  b -= 2;
  {
    int i = b * 256 + t;
    int p = positions[i], f = i >> 11;
    if (p > 0) atomicAdd(&counts[f * 2], 1);
    else if (p < 0) atomicAdd(&counts[f * 2 + 1], 1);
  }
}

// =====================================================================
// bf16 MFMA GEMM, 128x128, BK=32, XOR-swizzled LDS (slot = q ^ ((row>>1)&3)).
// Triple-buffered, depth-2 prefetch, counted vmcnt. epi 1: +bias,relu ;
// epi 3: +bias + fused per-row sum-of-squares -> tension.
// =====================================================================
__global__ __launch_bounds__(256) void gemm_bt(
    const u16* __restrict__ A, int lda,
    const u16* __restrict__ Bt, int ldb,
    u16* __restrict__ C, int ldc,
    const float* __restrict__ bias, int epi, int K,
    float* __restrict__ tension) {
  __shared__ __align__(16) u16 As[3][128 * 32];
  __shared__ __align__(16) u16 Bs[3][128 * 32];
  const int tid = threadIdx.x;
  const int m0 = blockIdx.x * 128;
  const int n0 = blockIdx.y * 128;
  f32x4 acc[4][4] = {};
  const int lane = tid & 63;
  const int w = tid >> 6;
  const int mw = (w & 1) * 64, nw = (w >> 1) * 64;
  const int fr = lane & 15;
  const int q = lane >> 4;
  const int ar0 = tid >> 2;                     // rows 0..63 (chunk tid), +64 for chunk tid+256
  const int ag = ((tid & 3) ^ ((ar0 >> 1) & 3)) * 8;  // (row+64)>>1 keeps same &3 -> ag reused

  const u16* aB0 = A + (size_t)(m0 + ar0) * lda + ag;
  const u16* aB1 = A + (size_t)(m0 + ar0 + 64) * lda + ag;
  const u16* bB0 = Bt + (size_t)(n0 + ar0) * ldb + ag;
  const u16* bB1 = Bt + (size_t)(n0 + ar0 + 64) * ldb + ag;

  auto stage = [&](int kk, int buf) {
    __builtin_amdgcn_global_load_lds(AS1(aB0 + kk), AS3(&As[buf][tid * 8]), 16, 0, 0);
    __builtin_amdgcn_global_load_lds(AS1(aB1 + kk), AS3(&As[buf][(tid + 256) * 8]), 16, 0, 0);
    __builtin_amdgcn_global_load_lds(AS1(bB0 + kk), AS3(&Bs[buf][tid * 8]), 16, 0, 0);
    __builtin_amdgcn_global_load_lds(AS1(bB1 + kk), AS3(&Bs[buf][(tid + 256) * 8]), 16, 0, 0);
  };

  const int NT = K >> 5;   // >= 8 for all calls
  stage(0, 0);
  stage(32, 1);
  int cur = 0, nxt = 1, nx2 = 2;
#pragma unroll 1
  for (int t = 0; t < NT; ++t) {
    if (t + 2 < NT) stage((t + 2) * 32, nx2);
    const int rem = NT - 1 - t;  // tiles newer than t in flight
    if (rem >= 2)      asm volatile("s_waitcnt vmcnt(8)" ::: "memory");
    else if (rem == 1) asm volatile("s_waitcnt vmcnt(4)" ::: "memory");
    else               asm volatile("s_waitcnt vmcnt(0)" ::: "memory");
    __builtin_amdgcn_s_barrier();          // tile t fully in LDS (all waves)
    asm volatile("" ::: "memory");
    bf16x8 af[4], bfv[4];
#pragma unroll
    for (int mt = 0; mt < 4; ++mt) {
      int r = mw + mt * 16 + fr;
      af[mt] = *reinterpret_cast<const bf16x8*>(&As[cur][r * 32 + ((q ^ ((r >> 1) & 3)) * 8)]);
    }
#pragma unroll
    for (int nt = 0; nt < 4; ++nt) {
      int r = nw + nt * 16 + fr;
      bfv[nt] = *reinterpret_cast<const bf16x8*>(&Bs[cur][r * 32 + ((q ^ ((r >> 1) & 3)) * 8)]);
    }
    __builtin_amdgcn_s_setprio(1);
#pragma unroll
    for (int mt = 0; mt < 4; ++mt)
#pragma unroll
      for (int nt = 0; nt < 4; ++nt)
        acc[mt][nt] = __builtin_amdgcn_mfma_f32_16x16x32_bf16(af[mt], bfv[nt], acc[mt][nt], 0, 0, 0);
    __builtin_amdgcn_s_setprio(0);
    asm volatile("s_waitcnt lgkmcnt(0)" ::: "memory");  // my ds_reads retired
    __builtin_amdgcn_s_barrier();          // buf[cur] safe to overwrite at t+1
    int tmp = cur; cur = nxt; nxt = nx2; nx2 = tmp;
  }
  const int rq = q * 4;  // D: col=lane&15, row=rq+reg [m89]
#pragma unroll
  for (int mt = 0; mt < 4; ++mt) {
    float srow[4] = {0.f, 0.f, 0.f, 0.f};
#pragma unroll
    for (int nt = 0; nt < 4; ++nt) {
      int col = n0 + nw + nt * 16 + fr;
      f32x4 v = acc[mt][nt];
#pragma unroll
      for (int r = 0; r < 4; ++r) {
        int row = m0 + mw + mt * 16 + rq + r;
        float val = v[r] + bias[col];
        if (epi == 1) val = val > 0.f ? val : 0.f;
        else srow[r] += val * val;
        C[(size_t)row * ldc + col] = f2bf(val);
      }
    }
    if (epi == 3) {
#pragma unroll
      for (int r = 0; r < 4; ++r) {
        float s = srow[r];
        s += __shfl_xor(s, 1, 16); s += __shfl_xor(s, 2, 16);
        s += __shfl_xor(s, 4, 16); s += __shfl_xor(s, 8, 16);
        if (fr == 0) atomicAdd(&tension[m0 + mw + mt * 16 + rq + r], s);
      }
    }
  }
}

// =====================================================================
// R15 fused GRU (= R12 proven version + mbase for split launch).
// 256 threads / 4 waves; block tile 128 rows x 64 j-cols x 4 regions; BK=64;
// wave = 64 rows x 32 j x 4 reg (acc = 128 AGPR). LDS 80KB -> 2 blk/CU.
// Layout [row][64] u16: slot' = slot ^ (row&7) via pre-swizzled global source.
// Per K-tile: ds ks0 | 24 MFMA | ds ks1 | lgkm0+bar | stage t+2 (10 gld)
// | 24 MFMA | vmcnt(10)+bar. Tiles 0..7: A=outbf, reg3=gi_n; 8..23: A=hidc,
// reg3=gh_n. WgruT k index = s*64 uniformly.
// =====================================================================
__global__ __launch_bounds__(256, 2) void gemm_gru(
    const u16* __restrict__ outbf, const u16* __restrict__ hidc,
    const u16* __restrict__ WgruT,
    const float* __restrict__ W_ihf, const float* __restrict__ bihf,
    const float* __restrict__ bhhf, const float* __restrict__ wealthf,
    const float* __restrict__ tension, u16* __restrict__ hpre, int mbase) {
  __shared__ __align__(16) u16 As[2][128 * 64];
  __shared__ __align__(16) u16 Bs[2][3][64 * 64];
  const int tid = threadIdx.x;
  const int m0 = mbase + blockIdx.x * 128;
  const int j0 = blockIdx.y * 64;
  f32x4 acc[4][4][2] = {};  // [region][mt][nt]
  const int lane = tid & 63;
  const int w = tid >> 6;
  const int mw = (w & 1) * 64, jw = (w >> 1) * 32;
  const int fr = lane & 15;
  const int q = lane >> 4;
  const int rowl = tid >> 3;
  const int koffT = ((tid & 7) ^ (rowl & 7)) * 8;
  const size_t aOutB = (size_t)(m0 + rowl) * 512 + koffT;
  const size_t aHidB = (size_t)(m0 + rowl) * 1024 + koffT;
  const size_t bB    = (size_t)(j0 + rowl) * 1536 + koffT;
  const int f7 = fr & 7;
  const int sk0 = (q ^ f7) * 8;
  const int sk1 = ((4 + q) ^ f7) * 8;

// s8 keeps the untaken branch's constant-folded address in-bounds (R11 fix).
#define STAGE(S, BUF)                                                                              \
  {                                                                                                \
    const int s8 = (S) < 8 ? (S) : (S) - 8;                                                        \
    const size_t kO = (size_t)(S) * 64;                                                            \
    const size_t kOA = (size_t)s8 * 64;                                                            \
    if ((S) < 8) {                                                                                 \
      _Pragma("unroll") for (int it = 0; it < 4; ++it)                                             \
          __builtin_amdgcn_global_load_lds(AS1(outbf + aOutB + (size_t)(32 * it) * 512 + kOA),     \
                                           AS3(&As[BUF][tid * 8 + it * 2048]), 16, 0, 0);          \
    } else {                                                                                       \
      _Pragma("unroll") for (int it = 0; it < 4; ++it)                                             \
          __builtin_amdgcn_global_load_lds(AS1(hidc + aHidB + (size_t)(32 * it) * 1024 + kOA),     \
                                           AS3(&As[BUF][tid * 8 + it * 2048]), 16, 0, 0);          \
    }                                                                                              \
    const u16* bp = WgruT + bB + kO;                                                               \
    __builtin_amdgcn_global_load_lds(AS1(bp), AS3(&Bs[BUF][0][tid * 8]), 16, 0, 0);                \
    __builtin_amdgcn_global_load_lds(AS1(bp + (size_t)32 * 1536),                                  \
                                     AS3(&Bs[BUF][0][tid * 8 + 2048]), 16, 0, 0);                  \
    __builtin_amdgcn_global_load_lds(AS1(bp + (size_t)1024 * 1536),                                \
                                     AS3(&Bs[BUF][1][tid * 8]), 16, 0, 0);                         \
    __builtin_amdgcn_global_load_lds(AS1(bp + (size_t)1056 * 1536),                                \
                                     AS3(&Bs[BUF][1][tid * 8 + 2048]), 16, 0, 0);                  \
    const size_t nOff = ((S) < 8 ? (size_t)2048 * 1536 : (size_t)3072 * 1536);                     \
    __builtin_amdgcn_global_load_lds(AS1(bp + nOff), AS3(&Bs[BUF][2][tid * 8]), 16, 0, 0);         \
    __builtin_amdgcn_global_load_lds(AS1(bp + nOff + (size_t)32 * 1536),                           \
                                     AS3(&Bs[BUF][2][tid * 8 + 2048]), 16, 0, 0);                  \
  }

#define GRU_STEP(T, REG3, CUR)                                                                     \
  {                                                                                                \
    bf16x8 af0[4], b00[2], b10[2], b20[2];                                                         \
    _Pragma("unroll") for (int mt = 0; mt < 4; ++mt)                                               \
        af0[mt] = *reinterpret_cast<const bf16x8*>(&As[CUR][(mw + mt * 16 + fr) * 64 + sk0]);      \
    _Pragma("unroll") for (int nt = 0; nt < 2; ++nt) {                                             \
      int rj = (jw + nt * 16 + fr) * 64 + sk0;                                                     \
      b00[nt] = *reinterpret_cast<const bf16x8*>(&Bs[CUR][0][rj]);                                 \
      b10[nt] = *reinterpret_cast<const bf16x8*>(&Bs[CUR][1][rj]);                                 \
      b20[nt] = *reinterpret_cast<const bf16x8*>(&Bs[CUR][2][rj]);                                 \
    }                                                                                              \
    __builtin_amdgcn_s_setprio(1);                                                                 \
    _Pragma("unroll") for (int mt = 0; mt < 4; ++mt)                                               \
        _Pragma("unroll") for (int nt = 0; nt < 2; ++nt) {                                         \
      acc[0][mt][nt] = __builtin_amdgcn_mfma_f32_16x16x32_bf16(af0[mt], b00[nt], acc[0][mt][nt], 0, 0, 0); \
      acc[1][mt][nt] = __builtin_amdgcn_mfma_f32_16x16x32_bf16(af0[mt], b10[nt], acc[1][mt][nt], 0, 0, 0); \
      acc[REG3][mt][nt] = __builtin_amdgcn_mfma_f32_16x16x32_bf16(af0[mt], b20[nt], acc[REG3][mt][nt], 0, 0, 0); \
    }                                                                                              \
    __builtin_amdgcn_s_setprio(0);                                                                 \
    bf16x8 af1[4], b01[2], b11[2], b21[2];                                                         \
    _Pragma("unroll") for (int mt = 0; mt < 4; ++mt)                                               \
        af1[mt] = *reinterpret_cast<const bf16x8*>(&As[CUR][(mw + mt * 16 + fr) * 64 + sk1]);      \
    _Pragma("unroll") for (int nt = 0; nt < 2; ++nt) {                                             \
      int rj = (jw + nt * 16 + fr) * 64 + sk1;                                                     \
      b01[nt] = *reinterpret_cast<const bf16x8*>(&Bs[CUR][0][rj]);                                 \
      b11[nt] = *reinterpret_cast<const bf16x8*>(&Bs[CUR][1][rj]);                                 \
      b21[nt] = *reinterpret_cast<const bf16x8*>(&Bs[CUR][2][rj]);                                 \
    }                                                                                              \
    asm volatile("s_waitcnt lgkmcnt(0)" ::: "memory");                                             \
    __builtin_amdgcn_s_barrier();                                                                  \
    asm volatile("" ::: "memory");                                                                 \
    if ((T) + 2 < 24) { STAGE((T) + 2, CUR) }                                                      \
    __builtin_amdgcn_s_setprio(1);                                                                 \
    _Pragma("unroll") for (int mt = 0; mt < 4; ++mt)                                               \
        _Pragma("unroll") for (int nt = 0; nt < 2; ++nt) {                                         \
      acc[0][mt][nt] = __builtin_amdgcn_mfma_f32_16x16x32_bf16(af1[mt], b01[nt], acc[0][mt][nt], 0, 0, 0); \
      acc[1][mt][nt] = __builtin_amdgcn_mfma_f32_16x16x32_bf16(af1[mt], b11[nt], acc[1][mt][nt], 0, 0, 0); \
      acc[REG3][mt][nt] = __builtin_amdgcn_mfma_f32_16x16x32_bf16(af1[mt], b21[nt], acc[REG3][mt][nt], 0, 0, 0); \
    }                                                                                              \
    __builtin_amdgcn_s_setprio(0);                                                                 \
    if ((T) + 2 < 24)      { asm volatile("s_waitcnt vmcnt(10)" ::: "memory"); }                   \
    else if ((T) + 1 < 24) { asm volatile("s_waitcnt vmcnt(0)" ::: "memory"); }                    \
    __builtin_amdgcn_s_barrier();                                                                  \
    asm volatile("" ::: "memory");                                                                 \
  }

  STAGE(0, 0)
  STAGE(1, 1)
  asm volatile("s_waitcnt vmcnt(10)" ::: "memory");
  __builtin_amdgcn_s_barrier();
  asm volatile("" ::: "memory");
#pragma unroll 1
  for (int T = 0; T < 8; T += 2) {   // tiles 0..7: reg3 = gi_n
    GRU_STEP(T, 2, 0)
    GRU_STEP(T + 1, 2, 1)
  }
#pragma unroll 1
  for (int T = 8; T < 24; T += 2) {  // tiles 8..23: reg3 = gh_n
    GRU_STEP(T, 3, 0)
    GRU_STEP(T + 1, 3, 1)
  }
#undef GRU_STEP
#undef STAGE

  // epilogue: D col=lane&15, row=(lane>>4)*4+reg [m89]
  const int rq = q * 4;
  const float* wt = W_ihf + (size_t)512 * 3072;  // tension row
  float wtr[2], wtz[2], wtn[2], bir[2], biz[2], bin_[2], bhr_[2], bhz_[2], bhn_[2];
#pragma unroll
  for (int nt = 0; nt < 2; ++nt) {
    int j = j0 + jw + nt * 16 + fr;
    wtr[nt] = wt[j]; wtz[nt] = wt[1024 + j]; wtn[nt] = wt[2048 + j];
    bir[nt] = bihf[j]; biz[nt] = bihf[1024 + j]; bin_[nt] = bihf[2048 + j];
    bhr_[nt] = bhhf[j]; bhz_[nt] = bhhf[1024 + j]; bhn_[nt] = bhhf[2048 + j];
  }
#pragma unroll
  for (int mt = 0; mt < 4; ++mt) {
#pragma unroll
    for (int rr = 0; rr < 4; ++rr) {
      int row = m0 + mw + mt * 16 + rq + rr;
      float tv = tension[row] * (1.f / 512.f);
      float wl = fminf(fmaxf(wealthf[row], 0.1f), 2.0f);
      float mod = 0.9f + 0.1f * wl;
#pragma unroll
      for (int nt = 0; nt < 2; ++nt) {
        int j = j0 + jw + nt * 16 + fr;
        float r = sigm(acc[0][mt][nt][rr] + tv * wtr[nt] + bir[nt] + bhr_[nt]);
        float z = sigm(acc[1][mt][nt][rr] + tv * wtz[nt] + biz[nt] + bhz_[nt]);
        float n = fast_tanh(acc[2][mt][nt][rr] + tv * wtn[nt] + bin_[nt]
                            + r * (acc[3][mt][nt][rr] + bhn_[nt]));
        float h = bf2f(hidc[(size_t)row * 1024 + j]);
        float h2 = (1.f - z) * n + z * h;
        h2 = fminf(fmaxf(h2 * mod, -10.f), 10.f);
        hpre[(size_t)row * 1024 + j] = f2bf(h2);
      }
    }
  }
}

// =====================================================================
__global__ void stats_kernel(const u16* __restrict__ hpre, const int* __restrict__ positions,
                             float* __restrict__ fsums) {
  int cc = blockIdx.x, f = blockIdx.y, z = blockIdx.z, t = threadIdx.x;
  int col = cc * 128 + (t & 127);
  int half = t >> 7;
  float st = 0, sp = 0, sm = 0;
  for (int it = 0; it < 128; ++it) {
    int row = (f << 11) + ((z * 128 + it) << 1) + half;
    int p = positions[row];
    float v = bf2f(hpre[(size_t)row * 1024 + col]);
    st += v;
    if (p > 0) sp += v;
    if (p < 0) sm += v;
  }
  atomicAdd(&fsums[(f * 3 + 0) * 1024 + col], st);
  atomicAdd(&fsums[(f * 3 + 1) * 1024 + col], sp);
  atomicAdd(&fsums[(f * 3 + 2) * 1024 + col], sm);
}

__global__ void derive_kernel(const float* __restrict__ fsums, const int* __restrict__ counts,
                              float* __restrict__ mean1, float* __restrict__ mean2,
                              float* __restrict__ fmean, float* __restrict__ gop,
                              float* __restrict__ scal) {
  int c = threadIdx.x;  // 1024
  int cnt1 = 0, cnt2 = 0, cf1[8], cf2[8];
#pragma unroll
  for (int f = 0; f < 8; ++f) {
    cf1[f] = counts[f * 2]; cf2[f] = counts[f * 2 + 1];
    cnt1 += cf1[f]; cnt2 += cf2[f];
  }
  float s1 = 0, s2 = 0;
#pragma unroll
  for (int f = 0; f < 8; ++f) { s1 += fsums[(f * 3 + 1) * 1024 + c]; s2 += fsums[(f * 3 + 2) * 1024 + c]; }
  float m1 = s1 / (float)(cnt1 > 1 ? cnt1 : 1);
  float m2 = s2 / (float)(cnt2 > 1 ? cnt2 : 1);
  float a1 = (cnt1 >= 2) ? 0.1f : 0.f;
  float a2 = (cnt2 >= 2) ? 0.1f : 0.f;
  float g = 0;
#pragma unroll
  for (int f = 0; f < 8; ++f) {
    float fm = (fsums[(f * 3) * 1024 + c]
                + a1 * ((float)cf1[f] * m1 - fsums[(f * 3 + 1) * 1024 + c])
                + a2 * ((float)cf2[f] * m2 - fsums[(f * 3 + 2) * 1024 + c])) * (1.f / 2048.f);
    fmean[f * 1024 + c] = fm;
    g += fm;
  }
  gop[c] = g * 0.125f;
  mean1[c] = m1; mean2[c] = m2;
  if (c == 0) { scal[0] = a1; scal[1] = a2; }
}

// 2048 blocks x 256 thr; block handles 8 rows x 1024 cols (4 col-slices).
__global__ void finalize_kernel(const u16* __restrict__ hpre, const int* __restrict__ positions,
                                const int* __restrict__ step, const float* __restrict__ mean1,
                                const float* __restrict__ mean2, const float* __restrict__ fmean,
                                const float* __restrict__ gop, const float* __restrict__ scal,
                                float* __restrict__ out) {
  int t = threadIdx.x;
  int r0 = blockIdx.x * 8;
  float s0 = scal[0], s1 = scal[1];
  bool step5 = step[0] > 5;
#pragma unroll 2
  for (int rr = 0; rr < 8; ++rr) {
    int row = r0 + rr;
    int p = positions[row];
    float w1 = (p > 0) ? s0 : 0.f;
    float w2 = (p < 0) ? s1 : 0.f;
    int f = row >> 11, qq = row & 2047;
    bool deb = step5 && (qq < 512);
    const u16* hrow = hpre + (size_t)row * 1024;
    const float* fmp = fmean + f * 1024;
    float* orow = out + 513 + (size_t)row * 1024;
#pragma unroll
    for (int e = 0; e < 4; ++e) {
      int c = e * 256 + t;
      float h = bf2f(hrow[c]);
      float hgs = h + w1 * (mean1[c] - h) + w2 * (mean2[c] - h);
      float hfs = 0.85f * hgs + 0.15f * fmp[c];
      orow[c] = deb ? (0.85f * hfs + 0.15f * gop[c]) : hfs;
    }
  }
}

__global__ void softmax_kernel(const float* __restrict__ tension, float* __restrict__ weights,
                               float* __restrict__ out) {
  __shared__ float red[1024];
  int t = threadIdx.x;
  float tv[16], mx = -1e30f, sumt = 0.f;
#pragma unroll
  for (int k = 0; k < 16; ++k) {
    tv[k] = tension[t + k * 1024] * (1.f / 512.f);
    mx = fmaxf(mx, tv[k]); sumt += tv[k];
  }
  red[t] = mx; __syncthreads();
  for (int s = 512; s > 0; s >>= 1) { if (t < s) red[t] = fmaxf(red[t], red[t + s]); __syncthreads(); }
  float m = red[0]; __syncthreads();
  red[t] = sumt; __syncthreads();
  for (int s = 512; s > 0; s >>= 1) { if (t < s) red[t] += red[t + s]; __syncthreads(); }
  float tot = red[0]; __syncthreads();
  float ev[16], se = 0.f;
#pragma unroll
  for (int k = 0; k < 16; ++k) { ev[k] = __expf(tv[k] - m); se += ev[k]; }
  red[t] = se; __syncthreads();
  for (int s = 512; s > 0; s >>= 1) { if (t < s) red[t] += red[t + s]; __syncthreads(); }
  float invS = 1.f / red[0];
#pragma unroll
  for (int k = 0; k < 16; ++k) weights[t + k * 1024] = ev[k] * invS;
  if (t == 0) out[512] = tot * (1.f / 16384.f);
}

__global__ void wsum_kernel(const float* __restrict__ weights, const u16* __restrict__ outbf,
                            float* __restrict__ co) {
  int b = blockIdx.x, t = threadIdx.x;
  int c = t * 2;
  float a0 = 0.f, a1 = 0.f;
  int i0 = b * 128;
  for (int i = i0; i < i0 + 128; ++i) {
    float w = weights[i];
    unsigned v = *reinterpret_cast<const unsigned*>(outbf + (size_t)i * 512 + c);
    a0 += w * bf2f(v & 0xffff);
    a1 += w * bf2f(v >> 16);
  }
  atomicAdd(&co[c], a0);
  atomicAdd(&co[c + 1], a1);
}

__global__ void pred_kernel(const float* __restrict__ co, const float* __restrict__ Wof,
                            const float* __restrict__ bof, float* __restrict__ out) {
  __shared__ float cs[512];
  int t = threadIdx.x, n = blockIdx.x * 256 + t;
  cs[t] = co[t]; cs[t + 256] = co[t + 256];
  __syncthreads();
  float acc = bof[n];
  for (int ck = 0; ck < 512; ++ck) acc += cs[ck] * Wof[(size_t)ck * 512 + n];
  out[n] = acc;
}

// =====================================================================
extern "C" void kernel_launch(void* const* d_in, const int* in_sizes, int n_in,
                              void* d_out, int out_size, void* d_ws, size_t ws_size,
                              hipStream_t stream) {
  const float* x      = (const float*)d_in[0];
  const float* hid    = (const float*)d_in[1];
  const float* wealth = (const float*)d_in[2];
  const float* Wa1    = (const float*)d_in[3];
  const float* ba1    = (const float*)d_in[4];
  const float* Wa2    = (const float*)d_in[5];
  const float* ba2    = (const float*)d_in[6];
  const float* Wg1    = (const float*)d_in[7];
  const float* bg1    = (const float*)d_in[8];
  const float* Wg2    = (const float*)d_in[9];
  const float* bg2    = (const float*)d_in[10];
  const float* W_ih   = (const float*)d_in[11];
  const float* W_hh   = (const float*)d_in[12];
  const float* b_ih   = (const float*)d_in[13];
  const float* b_hh   = (const float*)d_in[14];
  const float* Wo     = (const float*)d_in[15];
  const float* bo     = (const float*)d_in[16];
  const int* positions= (const int*)d_in[17];
  const int* step     = (const int*)d_in[18];
  float* out = (float*)d_out;  // [0,512) pred | [512] avg_tension | [513..) new_h

  char* w = (char*)d_ws;
  size_t off = 0;
  auto alloc = [&](size_t bytes) { void* p = w + off; off += (bytes + 255) & ~(size_t)255; return p; };
  u16*   hidc    = (u16*)  alloc((size_t)NC * 1024 * 2);
  u16*   outbf   = (u16*)  alloc((size_t)NC * 512 * 2);
  u16*   hpre    = (u16*)  alloc((size_t)NC * 1024 * 2);
  u16*   WgruT   = (u16*)  alloc((size_t)4096 * 1536 * 2);
  u16*   W1catT  = (u16*)  alloc((size_t)256 * 1024 * 2);
  u16*   W2catT  = (u16*)  alloc((size_t)512 * 256 * 2);
  u16*   t1      = (u16*)  alloc((size_t)NC * 256 * 2);
  // zeroed contiguous: bias1 | co | counts | fsums | tension
  float* bias1   = (float*)alloc(256 * 4);
  float* co      = (float*)alloc(512 * 4);
  int*   counts  = (int*)  alloc(16 * 4);
  float* fsums   = (float*)alloc(8 * 3 * 1024 * 4);
  float* tension = (float*)alloc(NC * 4);
  float* bias2   = (float*)alloc(512 * 4);
  float* weights = (float*)alloc(NC * 4);
  float* mean1   = (float*)alloc(1024 * 4);
  float* mean2   = (float*)alloc(1024 * 4);
  float* gop     = (float*)alloc(1024 * 4);
  float* fmean   = (float*)alloc(8 * 1024 * 4);
  float* scal    = (float*)alloc(8 * 4);

  (void)hipMemsetAsync(bias1, 0, 1024 + 2048 + 256 + 98304 + 65536, stream);

  prep_small<<<130, 256, 0, stream>>>(Wa1, Wg1, x, ba1, bg1, bias1, ba2, bg2, bias2,
                                      positions, counts);
  prep_cvt<<<2048, 256, 0, stream>>>(hid, hidc);
  prep_packT<<<1248, 256, 0, stream>>>(W_ih, W_hh, WgruT, Wa1, Wg1, W1catT,
                                       Wa2, Wg2, W2catT);

  // t1 = relu(h @ W1 + bias1)   M=16384 K=1024 N=256
  gemm_bt<<<dim3(128, 2), 256, 0, stream>>>(hidc, 1024, W1catT, 1024, t1, 256,
                                            bias1, 1, 1024, nullptr);
  // output = t1 @ [Wa2;-Wg2] + (ba2-bg2); fused tension
  gemm_bt<<<dim3(128, 4), 256, 0, stream>>>(t1, 256, W2catT, 256, outbf, 512,
                                            bias2, 3, 256, tension);

  // fused GRU (R12-proven, split into two m-half launches for attribution)
  gemm_gru<<<dim3(64, 16), 256, 0, stream>>>(outbf, hidc, WgruT, W_ih, b_ih, b_hh,
                                             wealth, tension, hpre, 0);
  gemm_gru<<<dim3(64, 16), 256, 0, stream>>>(outbf, hidc, WgruT, W_ih, b_ih, b_hh,
                                             wealth, tension, hpre, 8192);

  stats_kernel<<<dim3(8, 8, 8), 256, 0, stream>>>(hpre, positions, fsums);
  derive_kernel<<<1, 1024, 0, stream>>>(fsums, counts, mean1, mean2, fmean, gop, scal);
  finalize_kernel<<<2048, 256, 0, stream>>>(hpre, positions, step, mean1, mean2, fmean, gop,
                                            scal, out);

  softmax_kernel<<<1, 1024, 0, stream>>>(tension, weights, out);
  wsum_kernel<<<128, 256, 0, stream>>>(weights, outbf, co);
  pred_kernel<<<2, 256, 0, stream>>>(co, Wo, bo, out);

  (void)in_sizes; (void)n_in; (void)out_size; (void)ws_size;
}